// Round 3
// baseline (737.600 us; speedup 1.0000x reference)
//
#include <hip/hip_runtime.h>
#include <hip/hip_bf16.h>

// Problem constants
#define T_SEQ 2048
#define D_MODEL 4096
#define N_HEADS 32
#define K_HEADS 8
#define HEAD_DIM 128

typedef unsigned short u16;
typedef short sfrag8 __attribute__((ext_vector_type(8)));   // 8 bf16 (4 VGPRs)
typedef float ffrag4 __attribute__((ext_vector_type(4)));   // 4 f32 acc

#if defined(__has_builtin)
#  if __has_builtin(__builtin_amdgcn_exp2f)
#    define EXP2F(x) __builtin_amdgcn_exp2f(x)
#  else
#    define EXP2F(x) exp2f(x)
#  endif
#else
#  define EXP2F(x) exp2f(x)
#endif

// 1/sqrt(128) * log2(e): softmax in exp2 domain (same probabilities,
// one fewer mul per exp since v_exp_f32 IS exp2).
#define QSCALE_LOG2E 0.12751744900463627f

__device__ __forceinline__ float bf2f(u16 u) {
    return __uint_as_float(((unsigned int)u) << 16);
}
__device__ __forceinline__ u16 f2bf(float f) {
    unsigned int x = __float_as_uint(f);
    unsigned int r = (x + 0x7fffu + ((x >> 16) & 1u)) >> 16;  // RTNE
    return (u16)r;
}
__device__ __forceinline__ uint4 pack8(const float4 a, const float4 b) {
    uint4 r;
    r.x = (unsigned)f2bf(a.x) | ((unsigned)f2bf(a.y) << 16);
    r.y = (unsigned)f2bf(a.z) | ((unsigned)f2bf(a.w) << 16);
    r.z = (unsigned)f2bf(b.x) | ((unsigned)f2bf(b.y) << 16);
    r.w = (unsigned)f2bf(b.z) | ((unsigned)f2bf(b.w) << 16);
    return r;
}

// async global->LDS, 16B per lane.
__device__ __forceinline__ void gload_lds16(const u16* g, u16* l) {
    __builtin_amdgcn_global_load_lds(
        (const __attribute__((address_space(1))) void*)g,
        (__attribute__((address_space(3))) void*)l, 16, 0, 0);
}

// ---------------------------------------------------------------------------
// Prep: f32 -> bf16 elementwise convert (8 elems / thread).
// ---------------------------------------------------------------------------
__global__ __launch_bounds__(256) void convert_bf16(
    const float* __restrict__ X, u16* __restrict__ Y, int n8)
{
    const int i = blockIdx.x * 256 + threadIdx.x;
    if (i < n8) {
        float4 a = ((const float4*)X)[(size_t)i * 2];
        float4 b = ((const float4*)X)[(size_t)i * 2 + 1];
        ((uint4*)Y)[i] = pack8(a, b);
    }
}

// ---------------------------------------------------------------------------
// Prep: transpose + convert. W (R x C) f32 row-major -> WT (C x R) bf16.
// ---------------------------------------------------------------------------
__global__ __launch_bounds__(256) void transpose_f32_bf16(
    const float* __restrict__ W, u16* __restrict__ WT, int R, int C)
{
    __shared__ float Ts[64][65];
    const int t = threadIdx.x;
    const int c0 = blockIdx.x * 64, r0 = blockIdx.y * 64;
    const int rl = t >> 4, cl = (t & 15) * 4;
#pragma unroll
    for (int p = 0; p < 4; ++p) {
        const int r = p * 16 + rl;
        float4 v = *(const float4*)(W + (size_t)(r0 + r) * C + c0 + cl);
        Ts[r][cl] = v.x; Ts[r][cl + 1] = v.y; Ts[r][cl + 2] = v.z; Ts[r][cl + 3] = v.w;
    }
    __syncthreads();
    const int nl = t >> 2, k4 = (t & 3) * 16;
    u16 tmp[16];
#pragma unroll
    for (int j = 0; j < 16; ++j) tmp[j] = f2bf(Ts[k4 + j][nl]);
    u16* dst = WT + (size_t)(c0 + nl) * R + r0 + k4;
    *(uint4*)(dst) = *(uint4*)&tmp[0];
    *(uint4*)(dst + 8) = *(uint4*)&tmp[8];
}

// ---------------------------------------------------------------------------
// m97-structure GEMM: C(M x Nb) = A(M x Kd) * BT(Nb x Kd)^T, all bf16 in.
// Tile 128x128, BK=64, 4 waves. CMODE: 0 bf16 natural, 1 f32,
// 3 fused KV epilogue (n<1024 -> kbuf natural; n>=1024 -> vtbuf transposed).
// ---------------------------------------------------------------------------
template <int CMODE>
__global__ __launch_bounds__(256) void gemm_bt(
    const u16* __restrict__ A, const u16* __restrict__ BT,
    void* __restrict__ Cp, int M, int Nb, int Kd, int ldc)
{
    __shared__ __align__(16) u16 As[128 * 64];
    __shared__ __align__(16) u16 Bs[128 * 64];

    const int tid = threadIdx.x;
    const int lane = tid & 63;
    const int w = tid >> 6;
    const int wm = w >> 1, wn = w & 1;
    const int ln = lane & 15, quad = lane >> 4;

    const int m0 = blockIdx.y * 128, n0 = blockIdx.x * 128;

    size_t aoff[4], boff[4];
#pragma unroll
    for (int i = 0; i < 4; ++i) {
        const int row = (i * 4 + w) * 8 + (lane >> 3);
        const int cg = (lane & 7) ^ (lane >> 3);
        aoff[i] = (size_t)(m0 + row) * Kd + cg * 8;
        boff[i] = (size_t)(n0 + row) * Kd + cg * 8;
    }

    ffrag4 acc[4][4];
#pragma unroll
    for (int mi = 0; mi < 4; ++mi)
#pragma unroll
        for (int ni = 0; ni < 4; ++ni) acc[mi][ni] = (ffrag4){0.f, 0.f, 0.f, 0.f};

    for (int k0 = 0; k0 < Kd; k0 += 64) {
#pragma unroll
        for (int i = 0; i < 4; ++i) {
            gload_lds16(A + aoff[i] + k0, &As[(i * 4 + w) * 512]);
            gload_lds16(BT + boff[i] + k0, &Bs[(i * 4 + w) * 512]);
        }
        __syncthreads();

#pragma unroll
        for (int kk = 0; kk < 2; ++kk) {
            sfrag8 af[4], bfv[4];
#pragma unroll
            for (int mi = 0; mi < 4; ++mi) {
                const int row = wm * 64 + mi * 16 + ln;
                const int pc = ((kk * 4) | quad) ^ (ln & 7);
                af[mi] = *(const sfrag8*)&As[row * 64 + pc * 8];
            }
#pragma unroll
            for (int ni = 0; ni < 4; ++ni) {
                const int row = wn * 64 + ni * 16 + ln;
                const int pc = ((kk * 4) | quad) ^ (ln & 7);
                bfv[ni] = *(const sfrag8*)&Bs[row * 64 + pc * 8];
            }
#pragma unroll
            for (int mi = 0; mi < 4; ++mi)
#pragma unroll
                for (int ni = 0; ni < 4; ++ni)
                    acc[mi][ni] = __builtin_amdgcn_mfma_f32_16x16x32_bf16(
                        af[mi], bfv[ni], acc[mi][ni], 0, 0, 0);
        }
        __syncthreads();
    }

#pragma unroll
    for (int mi = 0; mi < 4; ++mi) {
#pragma unroll
        for (int ni = 0; ni < 4; ++ni) {
            const int gcol = n0 + wn * 64 + ni * 16 + ln;
#pragma unroll
            for (int i = 0; i < 4; ++i) {
                const int grow = m0 + wm * 64 + mi * 16 + quad * 4 + i;
                if constexpr (CMODE == 1) {
                    ((float*)Cp)[(size_t)grow * ldc + gcol] = acc[mi][ni][i];
                } else if constexpr (CMODE == 3) {
                    if (gcol < 1024) {
                        ((u16*)Cp)[(size_t)grow * 1024 + gcol] = f2bf(acc[mi][ni][i]);
                    } else {
                        ((u16*)Cp + 2097152)[(size_t)(gcol - 1024) * T_SEQ + grow] =
                            f2bf(acc[mi][ni][i]);
                    }
                } else {
                    ((u16*)Cp)[(size_t)grow * ldc + gcol] = f2bf(acc[mi][ni][i]);
                }
            }
        }
    }
}

// ---------------------------------------------------------------------------
// OLD GEMM (fallback path only).
// ---------------------------------------------------------------------------
template <int AMODE, int CMODE>
__global__ __launch_bounds__(256) void gemm_any(
    const void* __restrict__ Ap, const float* __restrict__ B, void* __restrict__ Cp,
    int M, int Nb, int Kd, int ldc)
{
    __shared__ __align__(16) u16 As[64 * 64];
    __shared__ __align__(16) u16 Bs[64 * 72];

    const int tid = threadIdx.x;
    const int n0 = blockIdx.x * 64, m0 = blockIdx.y * 64;

    const int lr = tid >> 3;
    const int cc8 = tid & 7;
    const int sw = ((cc8 ^ (lr & 7)) * 8);
    const int dstA0 = lr * 64 + sw;
    const int dstA1 = (lr + 32) * 64 + sw;
    const size_t arow0 = (size_t)(m0 + lr) * Kd;
    const size_t arow1 = (size_t)(m0 + lr + 32) * Kd;

    const int kr = tid >> 2;
    const int ncb = (tid & 3) * 16;

    const int lane = tid & 63;
    const int w = tid >> 6;
    const int col16 = lane & 15;
    const int quad = lane >> 4;
    const int swl = lane & 7;
    const int mrow = w * 16 + col16;

    ffrag4 acc[4];
#pragma unroll
    for (int j = 0; j < 4; ++j) acc[j] = (ffrag4){0.f, 0.f, 0.f, 0.f};

    for (int k0 = 0; k0 < Kd; k0 += 64) {
        if constexpr (AMODE == 1) {
            const u16* Af = (const u16*)Ap;
            uint4 va0 = *(const uint4*)(Af + arow0 + k0 + cc8 * 8);
            uint4 va1 = *(const uint4*)(Af + arow1 + k0 + cc8 * 8);
            *(uint4*)&As[dstA0] = va0;
            *(uint4*)&As[dstA1] = va1;
        } else {
            const float* Af = (const float*)Ap;
            float4 a00 = *(const float4*)(Af + arow0 + k0 + cc8 * 8);
            float4 a01 = *(const float4*)(Af + arow0 + k0 + cc8 * 8 + 4);
            float4 a10 = *(const float4*)(Af + arow1 + k0 + cc8 * 8);
            float4 a11 = *(const float4*)(Af + arow1 + k0 + cc8 * 8 + 4);
            *(uint4*)&As[dstA0] = pack8(a00, a01);
            *(uint4*)&As[dstA1] = pack8(a10, a11);
        }
        {
            const float* bp = B + (size_t)(k0 + kr) * Nb + n0 + ncb;
            float4 b0 = *(const float4*)(bp);
            float4 b1 = *(const float4*)(bp + 4);
            float4 b2 = *(const float4*)(bp + 8);
            float4 b3 = *(const float4*)(bp + 12);
            u16 tmp[16];
            tmp[0] = f2bf(b0.x); tmp[1] = f2bf(b0.y); tmp[2] = f2bf(b0.z); tmp[3] = f2bf(b0.w);
            tmp[4] = f2bf(b1.x); tmp[5] = f2bf(b1.y); tmp[6] = f2bf(b1.z); tmp[7] = f2bf(b1.w);
            tmp[8] = f2bf(b2.x); tmp[9] = f2bf(b2.y); tmp[10] = f2bf(b2.z); tmp[11] = f2bf(b2.w);
            tmp[12] = f2bf(b3.x); tmp[13] = f2bf(b3.y); tmp[14] = f2bf(b3.z); tmp[15] = f2bf(b3.w);
#pragma unroll
            for (int e = 0; e < 16; ++e)
                Bs[(ncb + e) * 72 + kr] = tmp[e];
        }
        __syncthreads();
#pragma unroll
        for (int c = 0; c < 2; ++c) {
            const int cc = c * 4 + quad;
            const int koffA = (cc ^ swl) * 8;
            sfrag8 af = *(const sfrag8*)&As[mrow * 64 + koffA];
#pragma unroll
            for (int j = 0; j < 4; ++j) {
                sfrag8 bfv = *(const sfrag8*)&Bs[(j * 16 + col16) * 72 + cc * 8];
                acc[j] = __builtin_amdgcn_mfma_f32_16x16x32_bf16(af, bfv, acc[j], 0, 0, 0);
            }
        }
        __syncthreads();
    }

#pragma unroll
    for (int j = 0; j < 4; ++j) {
        const int gcol = n0 + j * 16 + col16;
#pragma unroll
        for (int i = 0; i < 4; ++i) {
            const int grow = m0 + w * 16 + quad * 4 + i;
            if constexpr (CMODE == 1) {
                ((float*)Cp)[(size_t)grow * ldc + gcol] = acc[j][i];
            } else if constexpr (CMODE == 2) {
                ((u16*)Cp)[(size_t)gcol * ldc + grow] = f2bf(acc[j][i]);
            } else {
                ((u16*)Cp)[(size_t)grow * ldc + gcol] = f2bf(acc[j][i]);
            }
        }
    }
}

// ---------------------------------------------------------------------------
// RoPE in-place on (rows x nheads x HEAD_DIM) bf16. grid (nheads, rows).
// ---------------------------------------------------------------------------
__global__ __launch_bounds__(64) void rope_kernel(
    u16* __restrict__ buf, int nheads, int t0)
{
    const int h = blockIdx.x;
    const int t = blockIdx.y;
    u16* rowp = buf + ((size_t)t * nheads + h) * HEAD_DIM;
    const int i = threadIdx.x;  // 0..63
    const float p = (float)(t0 + t);
    const float inv = expf(-((float)i * (1.0f / 64.0f)) * 13.122363377404329f);
    const float ang = p * inv;
    const float c = cosf(ang);
    const float s = sinf(ang);
    const float x1 = bf2f(rowp[i]);
    const float x2 = bf2f(rowp[i + 64]);
    rowp[i] = f2bf(x1 * c - x2 * s);
    rowp[i + 64] = f2bf(x2 * c + x1 * s);
}

// ---------------------------------------------------------------------------
// MFMA flash attention, causal, GQA. grid (N_HEADS, Ts/64), block 256 (4
// waves). Round-1 verified structure + four algebra-identical deltas:
// (1) register prefetch of next K/V tile, (2) exp2-domain constant,
// (3) lane-local l partials (single final reduce), (4) exact-identity
// O-rescale skip when all alpha==1, (5) s_setprio around MFMA clusters.
// ---------------------------------------------------------------------------
__global__ __launch_bounds__(256) void attn_mfma(
    const u16* q, const u16* __restrict__ k,
    const u16* __restrict__ vt, u16* ctx, int t0)
{
    __shared__ __align__(16) u16 Kt[64 * 136];      // [key][d], pad 8
    __shared__ __align__(16) u16 Vt[128 * 72];      // [d][key], pad 8
    __shared__ __align__(16) u16 Ps[4][16 * 72];    // per-wave [q][key], pad 8

    const int head = blockIdx.x;
    const int qt = blockIdx.y;
    const int kvh = head >> 2;
    const int tid = threadIdx.x;
    const int lane = tid & 63;
    const int w = tid >> 6;          // wave id
    const int ln = lane & 15;
    const int quad = lane >> 4;

    // staging assignments
    const int kr = tid >> 2;         // 0..63  (K rows)
    const int c4 = (tid & 3) * 32;   // d-chunk for K
    const int vd = tid >> 1;         // 0..127 (Vt rows = dims)
    const int vh = (tid & 1) * 32;   // key-chunk for Vt

    // ---- prefetch first K/V tile into registers (T14) ----
    uint4 kreg[4], vreg[4];
    {
        const u16* kg = k + ((size_t)kr * K_HEADS + kvh) * HEAD_DIM + c4;
#pragma unroll
        for (int j = 0; j < 4; ++j) kreg[j] = *(const uint4*)(kg + j * 8);
        const u16* vg = vt + ((size_t)(kvh * 128 + vd)) * T_SEQ + vh;
#pragma unroll
        for (int j = 0; j < 4; ++j) vreg[j] = *(const uint4*)(vg + j * 8);
    }

    // Q fragments: A[m=ln][k=kk*32+quad*8+j]  (Q already roped)
    const int qrow_loc = qt * 64 + w * 16 + ln;
    sfrag8 qf[4];
    {
        const u16* qg = q + ((size_t)qrow_loc * N_HEADS + head) * HEAD_DIM;
#pragma unroll
        for (int kk = 0; kk < 4; ++kk)
            qf[kk] = *(const sfrag8*)(qg + kk * 32 + quad * 8);
    }

    ffrag4 acc_o[8];
#pragma unroll
    for (int dt = 0; dt < 8; ++dt) acc_o[dt] = (ffrag4){0.f, 0.f, 0.f, 0.f};
    float mrow[4] = {-INFINITY, -INFINITY, -INFINITY, -INFINITY};
    float lrow_l[4] = {0.f, 0.f, 0.f, 0.f};   // lane-local partial sums

    const int Tq0 = t0 + qt * 64;           // absolute base of q tile
    const int nst = Tq0 / 64 + 1;           // KV tiles incl. diagonal
    const int qabs_base = Tq0 + w * 16 + quad * 4;  // + i = abs q row

    for (int st = 0; st < nst; ++st) {
        const int kv0 = st * 64;
        const bool diag = (st == nst - 1);

        __syncthreads();   // prev tile compute done: LDS safe to overwrite
        {
            u16* kd = &Kt[kr * 136 + c4];
#pragma unroll
            for (int j = 0; j < 4; ++j) *(uint4*)(kd + j * 8) = kreg[j];
            u16* vdst = &Vt[vd * 72 + vh];
#pragma unroll
            for (int j = 0; j < 4; ++j) *(uint4*)(vdst + j * 8) = vreg[j];
        }
        __syncthreads();   // tiles ready

        // prefetch next tile (latency hides under this tile's compute)
        if (st + 1 < nst) {
            const int kv1 = kv0 + 64;
            const u16* kg = k + ((size_t)(kv1 + kr) * K_HEADS + kvh) * HEAD_DIM + c4;
#pragma unroll
            for (int j = 0; j < 4; ++j) kreg[j] = *(const uint4*)(kg + j * 8);
            const u16* vg = vt + ((size_t)(kvh * 128 + vd)) * T_SEQ + kv1 + vh;
#pragma unroll
            for (int j = 0; j < 4; ++j) vreg[j] = *(const uint4*)(vg + j * 8);
        }

        const int ktc = diag ? ((w < 2) ? 2 : 4) : 4;   // key subtiles computed
        // ---- S = Q K^T ----
        ffrag4 sacc[4];
        __builtin_amdgcn_s_setprio(1);
#pragma unroll
        for (int kt = 0; kt < 4; ++kt) {
            if (kt >= ktc) break;
            sacc[kt] = (ffrag4){0.f, 0.f, 0.f, 0.f};
#pragma unroll
            for (int kk = 0; kk < 4; ++kk) {
                sfrag8 bfr = *(const sfrag8*)&Kt[(kt * 16 + ln) * 136 + kk * 32 + quad * 8];
                sacc[kt] = __builtin_amdgcn_mfma_f32_16x16x32_bf16(qf[kk], bfr, sacc[kt], 0, 0, 0);
            }
        }
        __builtin_amdgcn_s_setprio(0);
        // ---- scale (exp2 domain) + causal mask ----
        float sv[4][4];
#pragma unroll
        for (int kt = 0; kt < 4; ++kt) {
            if (kt >= ktc) break;
            const int key_abs = kv0 + kt * 16 + ln;
#pragma unroll
            for (int i = 0; i < 4; ++i) {
                float s = sacc[kt][i] * QSCALE_LOG2E;
                if (diag && key_abs > qabs_base + i) s = -INFINITY;
                sv[kt][i] = s;
            }
        }
        // ---- tile row max (across kt and 16 lanes) ----
        float tm[4];
#pragma unroll
        for (int i = 0; i < 4; ++i) {
            float t = sv[0][i];
            for (int kt = 1; kt < ktc; ++kt) t = fmaxf(t, sv[kt][i]);
            t = fmaxf(t, __shfl_xor(t, 1));
            t = fmaxf(t, __shfl_xor(t, 2));
            t = fmaxf(t, __shfl_xor(t, 4));
            t = fmaxf(t, __shfl_xor(t, 8));
            tm[i] = t;
        }
        float alpha[4];
#pragma unroll
        for (int i = 0; i < 4; ++i) {
            const float mn = fmaxf(mrow[i], tm[i]);
            alpha[i] = EXP2F(mrow[i] - mn);
            mrow[i] = mn;
        }
        // ---- rescale O and l partials, skipped when all alpha == 1.0
        // (multiply-by-1.0 is a bitwise no-op, so skipping is exact) ----
        const bool noop = (alpha[0] == 1.f) && (alpha[1] == 1.f) &&
                          (alpha[2] == 1.f) && (alpha[3] == 1.f);
        if (!__all(noop)) {
#pragma unroll
            for (int i = 0; i < 4; ++i) {
                lrow_l[i] *= alpha[i];
#pragma unroll
                for (int dt = 0; dt < 8; ++dt) acc_o[dt][i] *= alpha[i];
            }
        }
        // ---- P = exp2(S - m), write to Ps, accumulate lane-local l ----
#pragma unroll
        for (int kt = 0; kt < 4; ++kt) {
            if (kt >= ktc) break;
#pragma unroll
            for (int i = 0; i < 4; ++i) {
                const float p = EXP2F(sv[kt][i] - mrow[i]);
                lrow_l[i] += p;
                Ps[w][(quad * 4 + i) * 72 + kt * 16 + ln] = f2bf(p);
            }
        }
        // ---- O += P V ----
        const int kbm = ktc >> 1;
        __builtin_amdgcn_s_setprio(1);
#pragma unroll
        for (int kb = 0; kb < 2; ++kb) {
            if (kb >= kbm) break;
            sfrag8 afr = *(const sfrag8*)&Ps[w][ln * 72 + kb * 32 + quad * 8];
#pragma unroll
            for (int dt = 0; dt < 8; ++dt) {
                sfrag8 bfr = *(const sfrag8*)&Vt[(dt * 16 + ln) * 72 + kb * 32 + quad * 8];
                acc_o[dt] = __builtin_amdgcn_mfma_f32_16x16x32_bf16(afr, bfr, acc_o[dt], 0, 0, 0);
            }
        }
        __builtin_amdgcn_s_setprio(0);
    }

    // ---- final l reduction (once) + write ctx ----
    float invl[4];
#pragma unroll
    for (int i = 0; i < 4; ++i) {
        float t = lrow_l[i];
        t += __shfl_xor(t, 1);
        t += __shfl_xor(t, 2);
        t += __shfl_xor(t, 4);
        t += __shfl_xor(t, 8);
        invl[i] = 1.0f / t;
    }
#pragma unroll
    for (int i = 0; i < 4; ++i) {
        u16* og = ctx + ((size_t)(qt * 64 + w * 16 + quad * 4 + i) * N_HEADS + head) * HEAD_DIM;
#pragma unroll
        for (int dt = 0; dt < 8; ++dt)
            og[dt * 16 + ln] = f2bf(acc_o[dt][i] * invl[i]);
    }
}

// ---------------------------------------------------------------------------
extern "C" void kernel_launch(void* const* d_in, const int* in_sizes, int n_in,
                              void* d_out, int out_size, void* d_ws, size_t ws_size,
                              hipStream_t stream) {
    (void)in_sizes; (void)n_in; (void)out_size;
    const float* x  = (const float*)d_in[0];
    const float* Wq = (const float*)d_in[2];
    const float* Wk = (const float*)d_in[3];
    const float* Wv = (const float*)d_in[4];
    const float* Wo = (const float*)d_in[5];
    float* out = (float*)d_out;
    char* ws = (char*)d_ws;
    const size_t MiB = 1024 * 1024;

    if (ws_size >= 88 * MiB) {
        // Layout: kbuf 0..4 | vtbuf 4..8 | qsl 8..24 | xb 24..40 |
        //         WkT 40..48 | WvT 48..56 | WshT (Wq then Wo) 56..88  [MiB]
        u16* kbuf  = (u16*)(ws);
        u16* vtbuf = (u16*)(ws + 4 * MiB);
        u16* qsl   = (u16*)(ws + 8 * MiB);
        u16* xb    = (u16*)(ws + 24 * MiB);
        u16* WkT   = (u16*)(ws + 40 * MiB);
        u16* WvT   = (u16*)(ws + 48 * MiB);
        u16* WshT  = (u16*)(ws + 56 * MiB);

        convert_bf16<<<dim3(T_SEQ * D_MODEL / 8 / 256), 256, 0, stream>>>(
            x, xb, T_SEQ * D_MODEL / 8);
        transpose_f32_bf16<<<dim3(16, 64), 256, 0, stream>>>(
            Wk, WkT, D_MODEL, K_HEADS * HEAD_DIM);
        transpose_f32_bf16<<<dim3(16, 64), 256, 0, stream>>>(
            Wv, WvT, D_MODEL, K_HEADS * HEAD_DIM);
        transpose_f32_bf16<<<dim3(64, 64), 256, 0, stream>>>(
            Wq, WshT, D_MODEL, N_HEADS * HEAD_DIM);

        // fused K+V projection over contiguous [WkT;WvT]
        gemm_bt<3><<<dim3(16, 16), 256, 0, stream>>>(
            xb, WkT, kbuf, T_SEQ, 2048, D_MODEL, 0);
        rope_kernel<<<dim3(K_HEADS, T_SEQ), 64, 0, stream>>>(kbuf, K_HEADS, 0);

        // Q projection + RoPE
        gemm_bt<0><<<dim3(32, 16), 256, 0, stream>>>(
            xb, WshT, qsl, T_SEQ, N_HEADS * HEAD_DIM, D_MODEL, N_HEADS * HEAD_DIM);
        rope_kernel<<<dim3(N_HEADS, T_SEQ), 64, 0, stream>>>(qsl, N_HEADS, 0);

        // attention (ctx in-place in qsl)
        attn_mfma<<<dim3(N_HEADS, T_SEQ / 64), 256, 0, stream>>>(
            qsl, kbuf, vtbuf, qsl, 0);

        // output projection
        transpose_f32_bf16<<<dim3(64, 64), 256, 0, stream>>>(
            Wo, WshT, N_HEADS * HEAD_DIM, D_MODEL);
        gemm_bt<1><<<dim3(32, 16), 256, 0, stream>>>(
            qsl, WshT, out, T_SEQ, D_MODEL, N_HEADS * HEAD_DIM, D_MODEL);
        return;
    }

    // ------------------- fallback: previous verified path -------------------
    u16* kbuf  = (u16*)(ws);                 // [t][kvh][d]   4,194,304 B
    u16* vtbuf = (u16*)(ws + 4194304);       // [kvh*128+d][t] 4,194,304 B
    u16* qsl   = (u16*)(ws + 8388608);       // [t][h][d] slice

    int S = 8;
    if (ws_size >= (size_t)8388608 + 16777216)      S = 1;
    else if (ws_size >= (size_t)8388608 + 8388608)  S = 2;
    else if (ws_size >= (size_t)8388608 + 4194304)  S = 4;
    const int Ts = T_SEQ / S;

    gemm_any<0, 0><<<dim3(16, T_SEQ / 64), 256, 0, stream>>>(
        x, Wk, kbuf, T_SEQ, K_HEADS * HEAD_DIM, D_MODEL, K_HEADS * HEAD_DIM);
    gemm_any<0, 2><<<dim3(16, T_SEQ / 64), 256, 0, stream>>>(
        x, Wv, vtbuf, T_SEQ, K_HEADS * HEAD_DIM, D_MODEL, T_SEQ);
    rope_kernel<<<dim3(K_HEADS, T_SEQ), 64, 0, stream>>>(kbuf, K_HEADS, 0);

    for (int s = 0; s < S; ++s) {
        const int t0 = s * Ts;
        gemm_any<0, 0><<<dim3(64, Ts / 64), 256, 0, stream>>>(
            x + (size_t)t0 * D_MODEL, Wq, qsl, Ts, D_MODEL, D_MODEL, D_MODEL);
        rope_kernel<<<dim3(N_HEADS, Ts), 64, 0, stream>>>(qsl, N_HEADS, t0);
        attn_mfma<<<dim3(N_HEADS, Ts / 64), 256, 0, stream>>>(
            qsl, kbuf, vtbuf, qsl, t0);
        gemm_any<1, 1><<<dim3(64, Ts / 64), 256, 0, stream>>>(
            qsl, Wo, out + (size_t)t0 * D_MODEL, Ts, D_MODEL, N_HEADS * HEAD_DIM, D_MODEL);
    }
}

// Round 4
// 607.323 us; speedup vs baseline: 1.2145x; 1.2145x over previous
//
#include <hip/hip_runtime.h>
#include <hip/hip_bf16.h>

// Problem constants
#define T_SEQ 2048
#define D_MODEL 4096
#define N_HEADS 32
#define K_HEADS 8
#define HEAD_DIM 128

typedef unsigned short u16;
typedef short sfrag8 __attribute__((ext_vector_type(8)));   // 8 bf16 (4 VGPRs)
typedef float ffrag4 __attribute__((ext_vector_type(4)));   // 4 f32 acc

#if defined(__has_builtin)
#  if __has_builtin(__builtin_amdgcn_exp2f)
#    define EXP2F(x) __builtin_amdgcn_exp2f(x)
#  else
#    define EXP2F(x) exp2f(x)
#  endif
#else
#  define EXP2F(x) exp2f(x)
#endif

// 1/sqrt(128) * log2(e): softmax in exp2 domain (same probabilities,
// one fewer mul per exp since v_exp_f32 IS exp2).
#define QSCALE_LOG2E 0.12751744900463627f

__device__ __forceinline__ float bf2f(u16 u) {
    return __uint_as_float(((unsigned int)u) << 16);
}
__device__ __forceinline__ u16 f2bf(float f) {
    unsigned int x = __float_as_uint(f);
    unsigned int r = (x + 0x7fffu + ((x >> 16) & 1u)) >> 16;  // RTNE
    return (u16)r;
}
__device__ __forceinline__ uint4 pack8(const float4 a, const float4 b) {
    uint4 r;
    r.x = (unsigned)f2bf(a.x) | ((unsigned)f2bf(a.y) << 16);
    r.y = (unsigned)f2bf(a.z) | ((unsigned)f2bf(a.w) << 16);
    r.z = (unsigned)f2bf(b.x) | ((unsigned)f2bf(b.y) << 16);
    r.w = (unsigned)f2bf(b.z) | ((unsigned)f2bf(b.w) << 16);
    return r;
}

// async global->LDS, 16B per lane.
__device__ __forceinline__ void gload_lds16(const u16* g, u16* l) {
    __builtin_amdgcn_global_load_lds(
        (const __attribute__((address_space(1))) void*)g,
        (__attribute__((address_space(3))) void*)l, 16, 0, 0);
}

// ---------------------------------------------------------------------------
// Prep: f32 -> bf16 elementwise convert (8 elems / thread).
// ---------------------------------------------------------------------------
__global__ __launch_bounds__(256) void convert_bf16(
    const float* __restrict__ X, u16* __restrict__ Y, int n8)
{
    const int i = blockIdx.x * 256 + threadIdx.x;
    if (i < n8) {
        float4 a = ((const float4*)X)[(size_t)i * 2];
        float4 b = ((const float4*)X)[(size_t)i * 2 + 1];
        ((uint4*)Y)[i] = pack8(a, b);
    }
}

// ---------------------------------------------------------------------------
// Prep: transpose + convert. W (R x C) f32 row-major -> WT (C x R) bf16.
// ---------------------------------------------------------------------------
__global__ __launch_bounds__(256) void transpose_f32_bf16(
    const float* __restrict__ W, u16* __restrict__ WT, int R, int C)
{
    __shared__ float Ts[64][65];
    const int t = threadIdx.x;
    const int c0 = blockIdx.x * 64, r0 = blockIdx.y * 64;
    const int rl = t >> 4, cl = (t & 15) * 4;
#pragma unroll
    for (int p = 0; p < 4; ++p) {
        const int r = p * 16 + rl;
        float4 v = *(const float4*)(W + (size_t)(r0 + r) * C + c0 + cl);
        Ts[r][cl] = v.x; Ts[r][cl + 1] = v.y; Ts[r][cl + 2] = v.z; Ts[r][cl + 3] = v.w;
    }
    __syncthreads();
    const int nl = t >> 2, k4 = (t & 3) * 16;
    u16 tmp[16];
#pragma unroll
    for (int j = 0; j < 16; ++j) tmp[j] = f2bf(Ts[k4 + j][nl]);
    u16* dst = WT + (size_t)(c0 + nl) * R + r0 + k4;
    *(uint4*)(dst) = *(uint4*)&tmp[0];
    *(uint4*)(dst + 8) = *(uint4*)&tmp[8];
}

// ---------------------------------------------------------------------------
// m97-structure GEMM: C(M x Nb) = A(M x Kd) * BT(Nb x Kd)^T, all bf16 in.
// Tile 128x128, BK=64, 4 waves. CMODE: 0 bf16 natural, 1 f32,
// 3 fused KV epilogue (n<1024 -> kbuf natural; n>=1024 -> vtbuf transposed).
// ---------------------------------------------------------------------------
template <int CMODE>
__global__ __launch_bounds__(256) void gemm_bt(
    const u16* __restrict__ A, const u16* __restrict__ BT,
    void* __restrict__ Cp, int M, int Nb, int Kd, int ldc)
{
    __shared__ __align__(16) u16 As[128 * 64];
    __shared__ __align__(16) u16 Bs[128 * 64];

    const int tid = threadIdx.x;
    const int lane = tid & 63;
    const int w = tid >> 6;
    const int wm = w >> 1, wn = w & 1;
    const int ln = lane & 15, quad = lane >> 4;

    const int m0 = blockIdx.y * 128, n0 = blockIdx.x * 128;

    size_t aoff[4], boff[4];
#pragma unroll
    for (int i = 0; i < 4; ++i) {
        const int row = (i * 4 + w) * 8 + (lane >> 3);
        const int cg = (lane & 7) ^ (lane >> 3);
        aoff[i] = (size_t)(m0 + row) * Kd + cg * 8;
        boff[i] = (size_t)(n0 + row) * Kd + cg * 8;
    }

    ffrag4 acc[4][4];
#pragma unroll
    for (int mi = 0; mi < 4; ++mi)
#pragma unroll
        for (int ni = 0; ni < 4; ++ni) acc[mi][ni] = (ffrag4){0.f, 0.f, 0.f, 0.f};

    for (int k0 = 0; k0 < Kd; k0 += 64) {
#pragma unroll
        for (int i = 0; i < 4; ++i) {
            gload_lds16(A + aoff[i] + k0, &As[(i * 4 + w) * 512]);
            gload_lds16(BT + boff[i] + k0, &Bs[(i * 4 + w) * 512]);
        }
        __syncthreads();

#pragma unroll
        for (int kk = 0; kk < 2; ++kk) {
            sfrag8 af[4], bfv[4];
#pragma unroll
            for (int mi = 0; mi < 4; ++mi) {
                const int row = wm * 64 + mi * 16 + ln;
                const int pc = ((kk * 4) | quad) ^ (ln & 7);
                af[mi] = *(const sfrag8*)&As[row * 64 + pc * 8];
            }
#pragma unroll
            for (int ni = 0; ni < 4; ++ni) {
                const int row = wn * 64 + ni * 16 + ln;
                const int pc = ((kk * 4) | quad) ^ (ln & 7);
                bfv[ni] = *(const sfrag8*)&Bs[row * 64 + pc * 8];
            }
#pragma unroll
            for (int mi = 0; mi < 4; ++mi)
#pragma unroll
                for (int ni = 0; ni < 4; ++ni)
                    acc[mi][ni] = __builtin_amdgcn_mfma_f32_16x16x32_bf16(
                        af[mi], bfv[ni], acc[mi][ni], 0, 0, 0);
        }
        __syncthreads();
    }

#pragma unroll
    for (int mi = 0; mi < 4; ++mi) {
#pragma unroll
        for (int ni = 0; ni < 4; ++ni) {
            const int gcol = n0 + wn * 64 + ni * 16 + ln;
#pragma unroll
            for (int i = 0; i < 4; ++i) {
                const int grow = m0 + wm * 64 + mi * 16 + quad * 4 + i;
                if constexpr (CMODE == 1) {
                    ((float*)Cp)[(size_t)grow * ldc + gcol] = acc[mi][ni][i];
                } else if constexpr (CMODE == 3) {
                    if (gcol < 1024) {
                        ((u16*)Cp)[(size_t)grow * 1024 + gcol] = f2bf(acc[mi][ni][i]);
                    } else {
                        ((u16*)Cp + 2097152)[(size_t)(gcol - 1024) * T_SEQ + grow] =
                            f2bf(acc[mi][ni][i]);
                    }
                } else {
                    ((u16*)Cp)[(size_t)grow * ldc + gcol] = f2bf(acc[mi][ni][i]);
                }
            }
        }
    }
}

// ---------------------------------------------------------------------------
// OLD GEMM (fallback path only).
// ---------------------------------------------------------------------------
template <int AMODE, int CMODE>
__global__ __launch_bounds__(256) void gemm_any(
    const void* __restrict__ Ap, const float* __restrict__ B, void* __restrict__ Cp,
    int M, int Nb, int Kd, int ldc)
{
    __shared__ __align__(16) u16 As[64 * 64];
    __shared__ __align__(16) u16 Bs[64 * 72];

    const int tid = threadIdx.x;
    const int n0 = blockIdx.x * 64, m0 = blockIdx.y * 64;

    const int lr = tid >> 3;
    const int cc8 = tid & 7;
    const int sw = ((cc8 ^ (lr & 7)) * 8);
    const int dstA0 = lr * 64 + sw;
    const int dstA1 = (lr + 32) * 64 + sw;
    const size_t arow0 = (size_t)(m0 + lr) * Kd;
    const size_t arow1 = (size_t)(m0 + lr + 32) * Kd;

    const int kr = tid >> 2;
    const int ncb = (tid & 3) * 16;

    const int lane = tid & 63;
    const int w = tid >> 6;
    const int col16 = lane & 15;
    const int quad = lane >> 4;
    const int swl = lane & 7;
    const int mrow = w * 16 + col16;

    ffrag4 acc[4];
#pragma unroll
    for (int j = 0; j < 4; ++j) acc[j] = (ffrag4){0.f, 0.f, 0.f, 0.f};

    for (int k0 = 0; k0 < Kd; k0 += 64) {
        if constexpr (AMODE == 1) {
            const u16* Af = (const u16*)Ap;
            uint4 va0 = *(const uint4*)(Af + arow0 + k0 + cc8 * 8);
            uint4 va1 = *(const uint4*)(Af + arow1 + k0 + cc8 * 8);
            *(uint4*)&As[dstA0] = va0;
            *(uint4*)&As[dstA1] = va1;
        } else {
            const float* Af = (const float*)Ap;
            float4 a00 = *(const float4*)(Af + arow0 + k0 + cc8 * 8);
            float4 a01 = *(const float4*)(Af + arow0 + k0 + cc8 * 8 + 4);
            float4 a10 = *(const float4*)(Af + arow1 + k0 + cc8 * 8);
            float4 a11 = *(const float4*)(Af + arow1 + k0 + cc8 * 8 + 4);
            *(uint4*)&As[dstA0] = pack8(a00, a01);
            *(uint4*)&As[dstA1] = pack8(a10, a11);
        }
        {
            const float* bp = B + (size_t)(k0 + kr) * Nb + n0 + ncb;
            float4 b0 = *(const float4*)(bp);
            float4 b1 = *(const float4*)(bp + 4);
            float4 b2 = *(const float4*)(bp + 8);
            float4 b3 = *(const float4*)(bp + 12);
            u16 tmp[16];
            tmp[0] = f2bf(b0.x); tmp[1] = f2bf(b0.y); tmp[2] = f2bf(b0.z); tmp[3] = f2bf(b0.w);
            tmp[4] = f2bf(b1.x); tmp[5] = f2bf(b1.y); tmp[6] = f2bf(b1.z); tmp[7] = f2bf(b1.w);
            tmp[8] = f2bf(b2.x); tmp[9] = f2bf(b2.y); tmp[10] = f2bf(b2.z); tmp[11] = f2bf(b2.w);
            tmp[12] = f2bf(b3.x); tmp[13] = f2bf(b3.y); tmp[14] = f2bf(b3.z); tmp[15] = f2bf(b3.w);
#pragma unroll
            for (int e = 0; e < 16; ++e)
                Bs[(ncb + e) * 72 + kr] = tmp[e];
        }
        __syncthreads();
#pragma unroll
        for (int c = 0; c < 2; ++c) {
            const int cc = c * 4 + quad;
            const int koffA = (cc ^ swl) * 8;
            sfrag8 af = *(const sfrag8*)&As[mrow * 64 + koffA];
#pragma unroll
            for (int j = 0; j < 4; ++j) {
                sfrag8 bfv = *(const sfrag8*)&Bs[(j * 16 + col16) * 72 + cc * 8];
                acc[j] = __builtin_amdgcn_mfma_f32_16x16x32_bf16(af, bfv, acc[j], 0, 0, 0);
            }
        }
        __syncthreads();
    }

#pragma unroll
    for (int j = 0; j < 4; ++j) {
        const int gcol = n0 + j * 16 + col16;
#pragma unroll
        for (int i = 0; i < 4; ++i) {
            const int grow = m0 + w * 16 + quad * 4 + i;
            if constexpr (CMODE == 1) {
                ((float*)Cp)[(size_t)grow * ldc + gcol] = acc[j][i];
            } else if constexpr (CMODE == 2) {
                ((u16*)Cp)[(size_t)gcol * ldc + grow] = f2bf(acc[j][i]);
            } else {
                ((u16*)Cp)[(size_t)grow * ldc + gcol] = f2bf(acc[j][i]);
            }
        }
    }
}

// ---------------------------------------------------------------------------
// RoPE in-place on (rows x nheads x HEAD_DIM) bf16. grid (nheads, rows).
// ---------------------------------------------------------------------------
__global__ __launch_bounds__(64) void rope_kernel(
    u16* __restrict__ buf, int nheads, int t0)
{
    const int h = blockIdx.x;
    const int t = blockIdx.y;
    u16* rowp = buf + ((size_t)t * nheads + h) * HEAD_DIM;
    const int i = threadIdx.x;  // 0..63
    const float p = (float)(t0 + t);
    const float inv = expf(-((float)i * (1.0f / 64.0f)) * 13.122363377404329f);
    const float ang = p * inv;
    const float c = cosf(ang);
    const float s = sinf(ang);
    const float x1 = bf2f(rowp[i]);
    const float x2 = bf2f(rowp[i + 64]);
    rowp[i] = f2bf(x1 * c - x2 * s);
    rowp[i + 64] = f2bf(x2 * c + x1 * s);
}

// ---------------------------------------------------------------------------
// MFMA flash attention, causal, GQA. grid (N_HEADS, Ts/64), block 256 (4
// waves). Round-1 verified staging (global->LDS between barriers, NO register
// prefetch -- round-3's prefetch caused per-iteration scratch spill: 393 MB
// HBM writes) + algebra-identical deltas: exp2-domain softmax, lane-local l
// partials, exact-identity rescale skip, s_setprio around MFMA clusters,
// longest-first qt remap (causal triangle: work ~ qt+1; start big blocks 1st).
// ---------------------------------------------------------------------------
__global__ __launch_bounds__(256) void attn_mfma(
    const u16* q, const u16* __restrict__ k,
    const u16* __restrict__ vt, u16* ctx, int t0)
{
    __shared__ __align__(16) u16 Kt[64 * 136];      // [key][d], pad 8
    __shared__ __align__(16) u16 Vt[128 * 72];      // [d][key], pad 8
    __shared__ __align__(16) u16 Ps[4][16 * 72];    // per-wave [q][key], pad 8

    const int head = blockIdx.x;
    const int qt = gridDim.y - 1 - blockIdx.y;      // longest-first dispatch
    const int kvh = head >> 2;
    const int tid = threadIdx.x;
    const int lane = tid & 63;
    const int w = tid >> 6;          // wave id
    const int ln = lane & 15;
    const int quad = lane >> 4;

    // staging assignments
    const int kr = tid >> 2;         // 0..63  (K rows)
    const int c4 = (tid & 3) * 32;   // d-chunk for K
    const int vd = tid >> 1;         // 0..127 (Vt rows = dims)
    const int vh = (tid & 1) * 32;   // key-chunk for Vt

    // Q fragments: A[m=ln][k=kk*32+quad*8+j]  (Q already roped)
    const int qrow_loc = qt * 64 + w * 16 + ln;
    sfrag8 qf[4];
    {
        const u16* qg = q + ((size_t)qrow_loc * N_HEADS + head) * HEAD_DIM;
#pragma unroll
        for (int kk = 0; kk < 4; ++kk)
            qf[kk] = *(const sfrag8*)(qg + kk * 32 + quad * 8);
    }

    ffrag4 acc_o[8];
#pragma unroll
    for (int dt = 0; dt < 8; ++dt) acc_o[dt] = (ffrag4){0.f, 0.f, 0.f, 0.f};
    float mrow[4] = {-INFINITY, -INFINITY, -INFINITY, -INFINITY};
    float lrow_l[4] = {0.f, 0.f, 0.f, 0.f};   // lane-local partial sums

    const int Tq0 = t0 + qt * 64;           // absolute base of q tile
    const int nst = Tq0 / 64 + 1;           // KV tiles incl. diagonal
    const int qabs_base = Tq0 + w * 16 + quad * 4;  // + i = abs q row

    for (int st = 0; st < nst; ++st) {
        const int kv0 = st * 64;
        const bool diag = (st == nst - 1);

        __syncthreads();   // prev tile compute done: LDS safe to overwrite
        // stage K tile: Kt[key][d]
        {
            const u16* kg = k + ((size_t)(kv0 + kr) * K_HEADS + kvh) * HEAD_DIM + c4;
            u16* kd = &Kt[kr * 136 + c4];
#pragma unroll
            for (int j = 0; j < 4; ++j)
                *(uint4*)(kd + j * 8) = *(const uint4*)(kg + j * 8);
        }
        // stage V tile transposed: Vt[d][key]
        {
            const u16* vg = vt + ((size_t)(kvh * 128 + vd)) * T_SEQ + kv0 + vh;
            u16* vdst = &Vt[vd * 72 + vh];
#pragma unroll
            for (int j = 0; j < 4; ++j)
                *(uint4*)(vdst + j * 8) = *(const uint4*)(vg + j * 8);
        }
        __syncthreads();   // tiles ready

        const int ktc = diag ? ((w < 2) ? 2 : 4) : 4;   // key subtiles computed
        // ---- S = Q K^T ----
        ffrag4 sacc[4];
        __builtin_amdgcn_s_setprio(1);
#pragma unroll
        for (int kt = 0; kt < 4; ++kt) {
            if (kt >= ktc) break;
            sacc[kt] = (ffrag4){0.f, 0.f, 0.f, 0.f};
#pragma unroll
            for (int kk = 0; kk < 4; ++kk) {
                sfrag8 bfr = *(const sfrag8*)&Kt[(kt * 16 + ln) * 136 + kk * 32 + quad * 8];
                sacc[kt] = __builtin_amdgcn_mfma_f32_16x16x32_bf16(qf[kk], bfr, sacc[kt], 0, 0, 0);
            }
        }
        __builtin_amdgcn_s_setprio(0);
        // ---- scale (exp2 domain) + causal mask ----
        float sv[4][4];
#pragma unroll
        for (int kt = 0; kt < 4; ++kt) {
            if (kt >= ktc) break;
            const int key_abs = kv0 + kt * 16 + ln;
#pragma unroll
            for (int i = 0; i < 4; ++i) {
                float s = sacc[kt][i] * QSCALE_LOG2E;
                if (diag && key_abs > qabs_base + i) s = -INFINITY;
                sv[kt][i] = s;
            }
        }
        // ---- tile row max (across kt and 16 lanes) ----
        float tm[4];
#pragma unroll
        for (int i = 0; i < 4; ++i) {
            float t = sv[0][i];
            for (int kt = 1; kt < ktc; ++kt) t = fmaxf(t, sv[kt][i]);
            t = fmaxf(t, __shfl_xor(t, 1));
            t = fmaxf(t, __shfl_xor(t, 2));
            t = fmaxf(t, __shfl_xor(t, 4));
            t = fmaxf(t, __shfl_xor(t, 8));
            tm[i] = t;
        }
        float alpha[4];
#pragma unroll
        for (int i = 0; i < 4; ++i) {
            const float mn = fmaxf(mrow[i], tm[i]);
            alpha[i] = EXP2F(mrow[i] - mn);
            mrow[i] = mn;
        }
        // ---- rescale O and l partials, skipped when all alpha == 1.0
        // (multiply-by-1.0 is a bitwise no-op, so skipping is exact) ----
        const bool noop = (alpha[0] == 1.f) && (alpha[1] == 1.f) &&
                          (alpha[2] == 1.f) && (alpha[3] == 1.f);
        if (!__all(noop)) {
#pragma unroll
            for (int i = 0; i < 4; ++i) {
                lrow_l[i] *= alpha[i];
#pragma unroll
                for (int dt = 0; dt < 8; ++dt) acc_o[dt][i] *= alpha[i];
            }
        }
        // ---- P = exp2(S - m), write to Ps, accumulate lane-local l ----
#pragma unroll
        for (int kt = 0; kt < 4; ++kt) {
            if (kt >= ktc) break;
#pragma unroll
            for (int i = 0; i < 4; ++i) {
                const float p = EXP2F(sv[kt][i] - mrow[i]);
                lrow_l[i] += p;
                Ps[w][(quad * 4 + i) * 72 + kt * 16 + ln] = f2bf(p);
            }
        }
        // ---- O += P V ----
        const int kbm = ktc >> 1;
        __builtin_amdgcn_s_setprio(1);
#pragma unroll
        for (int kb = 0; kb < 2; ++kb) {
            if (kb >= kbm) break;
            sfrag8 afr = *(const sfrag8*)&Ps[w][ln * 72 + kb * 32 + quad * 8];
#pragma unroll
            for (int dt = 0; dt < 8; ++dt) {
                sfrag8 bfr = *(const sfrag8*)&Vt[(dt * 16 + ln) * 72 + kb * 32 + quad * 8];
                acc_o[dt] = __builtin_amdgcn_mfma_f32_16x16x32_bf16(afr, bfr, acc_o[dt], 0, 0, 0);
            }
        }
        __builtin_amdgcn_s_setprio(0);
    }

    // ---- final l reduction (once) + write ctx ----
    float invl[4];
#pragma unroll
    for (int i = 0; i < 4; ++i) {
        float t = lrow_l[i];
        t += __shfl_xor(t, 1);
        t += __shfl_xor(t, 2);
        t += __shfl_xor(t, 4);
        t += __shfl_xor(t, 8);
        invl[i] = 1.0f / t;
    }
#pragma unroll
    for (int i = 0; i < 4; ++i) {
        u16* og = ctx + ((size_t)(qt * 64 + w * 16 + quad * 4 + i) * N_HEADS + head) * HEAD_DIM;
#pragma unroll
        for (int dt = 0; dt < 8; ++dt)
            og[dt * 16 + ln] = f2bf(acc_o[dt][i] * invl[i]);
    }
}

// ---------------------------------------------------------------------------
extern "C" void kernel_launch(void* const* d_in, const int* in_sizes, int n_in,
                              void* d_out, int out_size, void* d_ws, size_t ws_size,
                              hipStream_t stream) {
    (void)in_sizes; (void)n_in; (void)out_size;
    const float* x  = (const float*)d_in[0];
    const float* Wq = (const float*)d_in[2];
    const float* Wk = (const float*)d_in[3];
    const float* Wv = (const float*)d_in[4];
    const float* Wo = (const float*)d_in[5];
    float* out = (float*)d_out;
    char* ws = (char*)d_ws;
    const size_t MiB = 1024 * 1024;

    if (ws_size >= 88 * MiB) {
        // Layout: kbuf 0..4 | vtbuf 4..8 | qsl 8..24 | xb 24..40 |
        //         WkT 40..48 | WvT 48..56 | WshT (Wq then Wo) 56..88  [MiB]
        u16* kbuf  = (u16*)(ws);
        u16* vtbuf = (u16*)(ws + 4 * MiB);
        u16* qsl   = (u16*)(ws + 8 * MiB);
        u16* xb    = (u16*)(ws + 24 * MiB);
        u16* WkT   = (u16*)(ws + 40 * MiB);
        u16* WvT   = (u16*)(ws + 48 * MiB);
        u16* WshT  = (u16*)(ws + 56 * MiB);

        convert_bf16<<<dim3(T_SEQ * D_MODEL / 8 / 256), 256, 0, stream>>>(
            x, xb, T_SEQ * D_MODEL / 8);
        transpose_f32_bf16<<<dim3(16, 64), 256, 0, stream>>>(
            Wk, WkT, D_MODEL, K_HEADS * HEAD_DIM);
        transpose_f32_bf16<<<dim3(16, 64), 256, 0, stream>>>(
            Wv, WvT, D_MODEL, K_HEADS * HEAD_DIM);
        transpose_f32_bf16<<<dim3(64, 64), 256, 0, stream>>>(
            Wq, WshT, D_MODEL, N_HEADS * HEAD_DIM);

        // fused K+V projection over contiguous [WkT;WvT]
        gemm_bt<3><<<dim3(16, 16), 256, 0, stream>>>(
            xb, WkT, kbuf, T_SEQ, 2048, D_MODEL, 0);
        rope_kernel<<<dim3(K_HEADS, T_SEQ), 64, 0, stream>>>(kbuf, K_HEADS, 0);

        // Q projection + RoPE
        gemm_bt<0><<<dim3(32, 16), 256, 0, stream>>>(
            xb, WshT, qsl, T_SEQ, N_HEADS * HEAD_DIM, D_MODEL, N_HEADS * HEAD_DIM);
        rope_kernel<<<dim3(N_HEADS, T_SEQ), 64, 0, stream>>>(qsl, N_HEADS, 0);

        // attention (ctx in-place in qsl)
        attn_mfma<<<dim3(N_HEADS, T_SEQ / 64), 256, 0, stream>>>(
            qsl, kbuf, vtbuf, qsl, 0);

        // output projection
        transpose_f32_bf16<<<dim3(64, 64), 256, 0, stream>>>(
            Wo, WshT, N_HEADS * HEAD_DIM, D_MODEL);
        gemm_bt<1><<<dim3(32, 16), 256, 0, stream>>>(
            qsl, WshT, out, T_SEQ, D_MODEL, N_HEADS * HEAD_DIM, D_MODEL);
        return;
    }

    // ------------------- fallback: previous verified path -------------------
    u16* kbuf  = (u16*)(ws);                 // [t][kvh][d]   4,194,304 B
    u16* vtbuf = (u16*)(ws + 4194304);       // [kvh*128+d][t] 4,194,304 B
    u16* qsl   = (u16*)(ws + 8388608);       // [t][h][d] slice

    int S = 8;
    if (ws_size >= (size_t)8388608 + 16777216)      S = 1;
    else if (ws_size >= (size_t)8388608 + 8388608)  S = 2;
    else if (ws_size >= (size_t)8388608 + 4194304)  S = 4;
    const int Ts = T_SEQ / S;

    gemm_any<0, 0><<<dim3(16, T_SEQ / 64), 256, 0, stream>>>(
        x, Wk, kbuf, T_SEQ, K_HEADS * HEAD_DIM, D_MODEL, K_HEADS * HEAD_DIM);
    gemm_any<0, 2><<<dim3(16, T_SEQ / 64), 256, 0, stream>>>(
        x, Wv, vtbuf, T_SEQ, K_HEADS * HEAD_DIM, D_MODEL, T_SEQ);
    rope_kernel<<<dim3(K_HEADS, T_SEQ), 64, 0, stream>>>(kbuf, K_HEADS, 0);

    for (int s = 0; s < S; ++s) {
        const int t0 = s * Ts;
        gemm_any<0, 0><<<dim3(64, Ts / 64), 256, 0, stream>>>(
            x + (size_t)t0 * D_MODEL, Wq, qsl, Ts, D_MODEL, D_MODEL, D_MODEL);
        rope_kernel<<<dim3(N_HEADS, Ts), 64, 0, stream>>>(qsl, N_HEADS, t0);
        attn_mfma<<<dim3(N_HEADS, Ts / 64), 256, 0, stream>>>(
            qsl, kbuf, vtbuf, qsl, t0);
        gemm_any<1, 1><<<dim3(64, Ts / 64), 256, 0, stream>>>(
            qsl, Wo, out + (size_t)t0 * D_MODEL, Ts, D_MODEL, N_HEADS * HEAD_DIM, D_MODEL);
    }
}

// Round 5
// 549.698 us; speedup vs baseline: 1.3418x; 1.1048x over previous
//
#include <hip/hip_runtime.h>
#include <hip/hip_bf16.h>

// Problem constants
#define T_SEQ 2048
#define D_MODEL 4096
#define N_HEADS 32
#define K_HEADS 8
#define HEAD_DIM 128

typedef unsigned short u16;
typedef short sfrag8 __attribute__((ext_vector_type(8)));   // 8 bf16 (4 VGPRs)
typedef float ffrag4 __attribute__((ext_vector_type(4)));   // 4 f32 acc

#if defined(__has_builtin)
#  if __has_builtin(__builtin_amdgcn_exp2f)
#    define EXP2F(x) __builtin_amdgcn_exp2f(x)
#  else
#    define EXP2F(x) exp2f(x)
#  endif
#else
#  define EXP2F(x) exp2f(x)
#endif

// 1/sqrt(128) * log2(e): softmax in exp2 domain.
#define QSCALE_LOG2E 0.12751744900463627f

__device__ __forceinline__ float bf2f(u16 u) {
    return __uint_as_float(((unsigned int)u) << 16);
}
__device__ __forceinline__ u16 f2bf(float f) {
    unsigned int x = __float_as_uint(f);
    unsigned int r = (x + 0x7fffu + ((x >> 16) & 1u)) >> 16;  // RTNE
    return (u16)r;
}
__device__ __forceinline__ uint4 pack8(const float4 a, const float4 b) {
    uint4 r;
    r.x = (unsigned)f2bf(a.x) | ((unsigned)f2bf(a.y) << 16);
    r.y = (unsigned)f2bf(a.z) | ((unsigned)f2bf(a.w) << 16);
    r.z = (unsigned)f2bf(b.x) | ((unsigned)f2bf(b.y) << 16);
    r.w = (unsigned)f2bf(b.z) | ((unsigned)f2bf(b.w) << 16);
    return r;
}

// async global->LDS, 16B per lane.
__device__ __forceinline__ void gload_lds16(const u16* g, u16* l) {
    __builtin_amdgcn_global_load_lds(
        (const __attribute__((address_space(1))) void*)g,
        (__attribute__((address_space(3))) void*)l, 16, 0, 0);
}

// ---------------------------------------------------------------------------
// Prep: f32 -> bf16 elementwise convert (8 elems / thread).
// ---------------------------------------------------------------------------
__global__ __launch_bounds__(256) void convert_bf16(
    const float* __restrict__ X, u16* __restrict__ Y, int n8)
{
    const int i = blockIdx.x * 256 + threadIdx.x;
    if (i < n8) {
        float4 a = ((const float4*)X)[(size_t)i * 2];
        float4 b = ((const float4*)X)[(size_t)i * 2 + 1];
        ((uint4*)Y)[i] = pack8(a, b);
    }
}

// ---------------------------------------------------------------------------
// Prep: transpose + convert. W (R x C) f32 row-major -> WT (C x R) bf16.
// ---------------------------------------------------------------------------
__global__ __launch_bounds__(256) void transpose_f32_bf16(
    const float* __restrict__ W, u16* __restrict__ WT, int R, int C)
{
    __shared__ float Ts[64][65];
    const int t = threadIdx.x;
    const int c0 = blockIdx.x * 64, r0 = blockIdx.y * 64;
    const int rl = t >> 4, cl = (t & 15) * 4;
#pragma unroll
    for (int p = 0; p < 4; ++p) {
        const int r = p * 16 + rl;
        float4 v = *(const float4*)(W + (size_t)(r0 + r) * C + c0 + cl);
        Ts[r][cl] = v.x; Ts[r][cl + 1] = v.y; Ts[r][cl + 2] = v.z; Ts[r][cl + 3] = v.w;
    }
    __syncthreads();
    const int nl = t >> 2, k4 = (t & 3) * 16;
    u16 tmp[16];
#pragma unroll
    for (int j = 0; j < 16; ++j) tmp[j] = f2bf(Ts[k4 + j][nl]);
    u16* dst = WT + (size_t)(c0 + nl) * R + r0 + k4;
    *(uint4*)(dst) = *(uint4*)&tmp[0];
    *(uint4*)(dst + 8) = *(uint4*)&tmp[8];
}

// ---------------------------------------------------------------------------
// m97-structure GEMM: C(M x Nb) = A(M x Kd) * BT(Nb x Kd)^T, all bf16 in.
// Tile 128x128, BK=64, 4 waves. XCD-aware bijective block swizzle (grid size
// must be a multiple of 8 -- true for all launches here).
// CMODE: 0 bf16 natural (ldc), 1 f32 (ldc),
//        4 fused QKV epilogue: Cp = workspace base.
//          gcol < 4096          -> qsl  (ws+8MiB)  [t][4096] bf16
//          4096 <= gcol < 5120  -> kbuf (ws+0)     [t][1024] bf16
//          gcol >= 5120         -> vtbuf(ws+4MiB)  [kvd][T_SEQ] bf16 (transposed)
// ---------------------------------------------------------------------------
template <int CMODE>
__global__ __launch_bounds__(256) void gemm_bt(
    const u16* __restrict__ A, const u16* __restrict__ BT,
    void* __restrict__ Cp, int M, int Nb, int Kd, int ldc)
{
    __shared__ __align__(16) u16 As[128 * 64];
    __shared__ __align__(16) u16 Bs[128 * 64];

    const int tid = threadIdx.x;
    const int lane = tid & 63;
    const int w = tid >> 6;
    const int wm = w >> 1, wn = w & 1;
    const int ln = lane & 15, quad = lane >> 4;

    // XCD-aware swizzle: contiguous chunk of blocks per XCD (bijective,
    // nwg % 8 == 0 for all launches of this kernel).
    int wid = blockIdx.y * gridDim.x + blockIdx.x;
    const int nwg = gridDim.x * gridDim.y;
    const int cpx = nwg >> 3;
    wid = (wid & 7) * cpx + (wid >> 3);
    const int bx = wid % gridDim.x;
    const int by = wid / gridDim.x;

    const int m0 = by * 128, n0 = bx * 128;

    size_t aoff[4], boff[4];
#pragma unroll
    for (int i = 0; i < 4; ++i) {
        const int row = (i * 4 + w) * 8 + (lane >> 3);
        const int cg = (lane & 7) ^ (lane >> 3);
        aoff[i] = (size_t)(m0 + row) * Kd + cg * 8;
        boff[i] = (size_t)(n0 + row) * Kd + cg * 8;
    }

    ffrag4 acc[4][4];
#pragma unroll
    for (int mi = 0; mi < 4; ++mi)
#pragma unroll
        for (int ni = 0; ni < 4; ++ni) acc[mi][ni] = (ffrag4){0.f, 0.f, 0.f, 0.f};

    for (int k0 = 0; k0 < Kd; k0 += 64) {
#pragma unroll
        for (int i = 0; i < 4; ++i) {
            gload_lds16(A + aoff[i] + k0, &As[(i * 4 + w) * 512]);
            gload_lds16(BT + boff[i] + k0, &Bs[(i * 4 + w) * 512]);
        }
        __syncthreads();

#pragma unroll
        for (int kk = 0; kk < 2; ++kk) {
            sfrag8 af[4], bfv[4];
#pragma unroll
            for (int mi = 0; mi < 4; ++mi) {
                const int row = wm * 64 + mi * 16 + ln;
                const int pc = ((kk * 4) | quad) ^ (ln & 7);
                af[mi] = *(const sfrag8*)&As[row * 64 + pc * 8];
            }
#pragma unroll
            for (int ni = 0; ni < 4; ++ni) {
                const int row = wn * 64 + ni * 16 + ln;
                const int pc = ((kk * 4) | quad) ^ (ln & 7);
                bfv[ni] = *(const sfrag8*)&Bs[row * 64 + pc * 8];
            }
#pragma unroll
            for (int mi = 0; mi < 4; ++mi)
#pragma unroll
                for (int ni = 0; ni < 4; ++ni)
                    acc[mi][ni] = __builtin_amdgcn_mfma_f32_16x16x32_bf16(
                        af[mi], bfv[ni], acc[mi][ni], 0, 0, 0);
        }
        __syncthreads();
    }

#pragma unroll
    for (int mi = 0; mi < 4; ++mi) {
#pragma unroll
        for (int ni = 0; ni < 4; ++ni) {
            const int gcol = n0 + wn * 64 + ni * 16 + ln;
#pragma unroll
            for (int i = 0; i < 4; ++i) {
                const int grow = m0 + wm * 64 + mi * 16 + quad * 4 + i;
                if constexpr (CMODE == 1) {
                    ((float*)Cp)[(size_t)grow * ldc + gcol] = acc[mi][ni][i];
                } else if constexpr (CMODE == 4) {
                    u16* base = (u16*)Cp;   // workspace base
                    const u16 v = f2bf(acc[mi][ni][i]);
                    if (gcol < 4096) {              // qsl at ws+8MiB
                        base[4194304u + (size_t)grow * 4096 + gcol] = v;
                    } else if (gcol < 5120) {       // kbuf at ws+0
                        base[(size_t)grow * 1024 + (gcol - 4096)] = v;
                    } else {                        // vtbuf at ws+4MiB, transposed
                        base[2097152u + (size_t)(gcol - 5120) * T_SEQ + grow] = v;
                    }
                } else {
                    ((u16*)Cp)[(size_t)grow * ldc + gcol] = f2bf(acc[mi][ni][i]);
                }
            }
        }
    }
}

// ---------------------------------------------------------------------------
// OLD GEMM (fallback path only).
// ---------------------------------------------------------------------------
template <int AMODE, int CMODE>
__global__ __launch_bounds__(256) void gemm_any(
    const void* __restrict__ Ap, const float* __restrict__ B, void* __restrict__ Cp,
    int M, int Nb, int Kd, int ldc)
{
    __shared__ __align__(16) u16 As[64 * 64];
    __shared__ __align__(16) u16 Bs[64 * 72];

    const int tid = threadIdx.x;
    const int n0 = blockIdx.x * 64, m0 = blockIdx.y * 64;

    const int lr = tid >> 3;
    const int cc8 = tid & 7;
    const int sw = ((cc8 ^ (lr & 7)) * 8);
    const int dstA0 = lr * 64 + sw;
    const int dstA1 = (lr + 32) * 64 + sw;
    const size_t arow0 = (size_t)(m0 + lr) * Kd;
    const size_t arow1 = (size_t)(m0 + lr + 32) * Kd;

    const int kr = tid >> 2;
    const int ncb = (tid & 3) * 16;

    const int lane = tid & 63;
    const int w = tid >> 6;
    const int col16 = lane & 15;
    const int quad = lane >> 4;
    const int swl = lane & 7;
    const int mrow = w * 16 + col16;

    ffrag4 acc[4];
#pragma unroll
    for (int j = 0; j < 4; ++j) acc[j] = (ffrag4){0.f, 0.f, 0.f, 0.f};

    for (int k0 = 0; k0 < Kd; k0 += 64) {
        if constexpr (AMODE == 1) {
            const u16* Af = (const u16*)Ap;
            uint4 va0 = *(const uint4*)(Af + arow0 + k0 + cc8 * 8);
            uint4 va1 = *(const uint4*)(Af + arow1 + k0 + cc8 * 8);
            *(uint4*)&As[dstA0] = va0;
            *(uint4*)&As[dstA1] = va1;
        } else {
            const float* Af = (const float*)Ap;
            float4 a00 = *(const float4*)(Af + arow0 + k0 + cc8 * 8);
            float4 a01 = *(const float4*)(Af + arow0 + k0 + cc8 * 8 + 4);
            float4 a10 = *(const float4*)(Af + arow1 + k0 + cc8 * 8);
            float4 a11 = *(const float4*)(Af + arow1 + k0 + cc8 * 8 + 4);
            *(uint4*)&As[dstA0] = pack8(a00, a01);
            *(uint4*)&As[dstA1] = pack8(a10, a11);
        }
        {
            const float* bp = B + (size_t)(k0 + kr) * Nb + n0 + ncb;
            float4 b0 = *(const float4*)(bp);
            float4 b1 = *(const float4*)(bp + 4);
            float4 b2 = *(const float4*)(bp + 8);
            float4 b3 = *(const float4*)(bp + 12);
            u16 tmp[16];
            tmp[0] = f2bf(b0.x); tmp[1] = f2bf(b0.y); tmp[2] = f2bf(b0.z); tmp[3] = f2bf(b0.w);
            tmp[4] = f2bf(b1.x); tmp[5] = f2bf(b1.y); tmp[6] = f2bf(b1.z); tmp[7] = f2bf(b1.w);
            tmp[8] = f2bf(b2.x); tmp[9] = f2bf(b2.y); tmp[10] = f2bf(b2.z); tmp[11] = f2bf(b2.w);
            tmp[12] = f2bf(b3.x); tmp[13] = f2bf(b3.y); tmp[14] = f2bf(b3.z); tmp[15] = f2bf(b3.w);
#pragma unroll
            for (int e = 0; e < 16; ++e)
                Bs[(ncb + e) * 72 + kr] = tmp[e];
        }
        __syncthreads();
#pragma unroll
        for (int c = 0; c < 2; ++c) {
            const int cc = c * 4 + quad;
            const int koffA = (cc ^ swl) * 8;
            sfrag8 af = *(const sfrag8*)&As[mrow * 64 + koffA];
#pragma unroll
            for (int j = 0; j < 4; ++j) {
                sfrag8 bfv = *(const sfrag8*)&Bs[(j * 16 + col16) * 72 + cc * 8];
                acc[j] = __builtin_amdgcn_mfma_f32_16x16x32_bf16(af, bfv, acc[j], 0, 0, 0);
            }
        }
        __syncthreads();
    }

#pragma unroll
    for (int j = 0; j < 4; ++j) {
        const int gcol = n0 + j * 16 + col16;
#pragma unroll
        for (int i = 0; i < 4; ++i) {
            const int grow = m0 + w * 16 + quad * 4 + i;
            if constexpr (CMODE == 1) {
                ((float*)Cp)[(size_t)grow * ldc + gcol] = acc[j][i];
            } else if constexpr (CMODE == 2) {
                ((u16*)Cp)[(size_t)gcol * ldc + grow] = f2bf(acc[j][i]);
            } else {
                ((u16*)Cp)[(size_t)grow * ldc + gcol] = f2bf(acc[j][i]);
            }
        }
    }
}

// ---------------------------------------------------------------------------
// RoPE in-place on (rows x nheads x HEAD_DIM) bf16. grid (nheads, rows).
// ---------------------------------------------------------------------------
__global__ __launch_bounds__(64) void rope_kernel(
    u16* __restrict__ buf, int nheads, int t0)
{
    const int h = blockIdx.x;
    const int t = blockIdx.y;
    u16* rowp = buf + ((size_t)t * nheads + h) * HEAD_DIM;
    const int i = threadIdx.x;  // 0..63
    const float p = (float)(t0 + t);
    const float inv = expf(-((float)i * (1.0f / 64.0f)) * 13.122363377404329f);
    const float ang = p * inv;
    const float c = cosf(ang);
    const float s = sinf(ang);
    const float x1 = bf2f(rowp[i]);
    const float x2 = bf2f(rowp[i + 64]);
    rowp[i] = f2bf(x1 * c - x2 * s);
    rowp[i + 64] = f2bf(x2 * c + x1 * s);
}

// ---------------------------------------------------------------------------
// MFMA flash attention, causal, GQA. grid (N_HEADS, Ts/64), block 256 (4
// waves). Round-4 verified structure + defer-max (T13, THR=8): skip the
// shfl max-reduce and rescale entirely unless some score exceeds the running
// max by >8 (exp2 units; P then bounded by 2^8 -- exact flash algebra since
// the same m is used for P, l, and O). First tile always takes the full path.
// ---------------------------------------------------------------------------
__global__ __launch_bounds__(256) void attn_mfma(
    const u16* q, const u16* __restrict__ k,
    const u16* __restrict__ vt, u16* ctx, int t0)
{
    __shared__ __align__(16) u16 Kt[64 * 136];      // [key][d], pad 8
    __shared__ __align__(16) u16 Vt[128 * 72];      // [d][key], pad 8
    __shared__ __align__(16) u16 Ps[4][16 * 72];    // per-wave [q][key], pad 8

    const int head = blockIdx.x;
    const int qt = gridDim.y - 1 - blockIdx.y;      // longest-first dispatch
    const int kvh = head >> 2;
    const int tid = threadIdx.x;
    const int lane = tid & 63;
    const int w = tid >> 6;          // wave id
    const int ln = lane & 15;
    const int quad = lane >> 4;

    // staging assignments
    const int kr = tid >> 2;         // 0..63  (K rows)
    const int c4 = (tid & 3) * 32;   // d-chunk for K
    const int vd = tid >> 1;         // 0..127 (Vt rows = dims)
    const int vh = (tid & 1) * 32;   // key-chunk for Vt

    // Q fragments: A[m=ln][k=kk*32+quad*8+j]  (Q already roped)
    const int qrow_loc = qt * 64 + w * 16 + ln;
    sfrag8 qf[4];
    {
        const u16* qg = q + ((size_t)qrow_loc * N_HEADS + head) * HEAD_DIM;
#pragma unroll
        for (int kk = 0; kk < 4; ++kk)
            qf[kk] = *(const sfrag8*)(qg + kk * 32 + quad * 8);
    }

    ffrag4 acc_o[8];
#pragma unroll
    for (int dt = 0; dt < 8; ++dt) acc_o[dt] = (ffrag4){0.f, 0.f, 0.f, 0.f};
    float mrow[4] = {-INFINITY, -INFINITY, -INFINITY, -INFINITY};
    float lrow_l[4] = {0.f, 0.f, 0.f, 0.f};   // lane-local partial sums

    const int Tq0 = t0 + qt * 64;           // absolute base of q tile
    const int nst = Tq0 / 64 + 1;           // KV tiles incl. diagonal
    const int qabs_base = Tq0 + w * 16 + quad * 4;  // + i = abs q row

    for (int st = 0; st < nst; ++st) {
        const int kv0 = st * 64;
        const bool diag = (st == nst - 1);

        __syncthreads();   // prev tile compute done: LDS safe to overwrite
        // stage K tile: Kt[key][d]
        {
            const u16* kg = k + ((size_t)(kv0 + kr) * K_HEADS + kvh) * HEAD_DIM + c4;
            u16* kd = &Kt[kr * 136 + c4];
#pragma unroll
            for (int j = 0; j < 4; ++j)
                *(uint4*)(kd + j * 8) = *(const uint4*)(kg + j * 8);
        }
        // stage V tile transposed: Vt[d][key]
        {
            const u16* vg = vt + ((size_t)(kvh * 128 + vd)) * T_SEQ + kv0 + vh;
            u16* vdst = &Vt[vd * 72 + vh];
#pragma unroll
            for (int j = 0; j < 4; ++j)
                *(uint4*)(vdst + j * 8) = *(const uint4*)(vg + j * 8);
        }
        __syncthreads();   // tiles ready

        const int ktc = diag ? ((w < 2) ? 2 : 4) : 4;   // key subtiles computed
        // ---- S = Q K^T ----
        ffrag4 sacc[4];
        __builtin_amdgcn_s_setprio(1);
#pragma unroll
        for (int kt = 0; kt < 4; ++kt) {
            if (kt >= ktc) break;
            sacc[kt] = (ffrag4){0.f, 0.f, 0.f, 0.f};
#pragma unroll
            for (int kk = 0; kk < 4; ++kk) {
                sfrag8 bfr = *(const sfrag8*)&Kt[(kt * 16 + ln) * 136 + kk * 32 + quad * 8];
                sacc[kt] = __builtin_amdgcn_mfma_f32_16x16x32_bf16(qf[kk], bfr, sacc[kt], 0, 0, 0);
            }
        }
        __builtin_amdgcn_s_setprio(0);
        // ---- scale (exp2 domain) + causal mask ----
        float sv[4][4];
#pragma unroll
        for (int kt = 0; kt < 4; ++kt) {
            if (kt >= ktc) break;
            const int key_abs = kv0 + kt * 16 + ln;
#pragma unroll
            for (int i = 0; i < 4; ++i) {
                float s = sacc[kt][i] * QSCALE_LOG2E;
                if (diag && key_abs > qabs_base + i) s = -INFINITY;
                sv[kt][i] = s;
            }
        }
        // ---- defer-max (T13): only reduce/rescale when max grew > THR ----
        bool grew = false;
#pragma unroll
        for (int kt = 0; kt < 4; ++kt) {
            if (kt >= ktc) break;
#pragma unroll
            for (int i = 0; i < 4; ++i)
                grew |= (sv[kt][i] > mrow[i] + 8.0f);
        }
        if (__any(grew)) {
            // full path: tile row max (across kt and 16 lanes)
            float tm[4];
#pragma unroll
            for (int i = 0; i < 4; ++i) {
                float t = sv[0][i];
                for (int kt = 1; kt < ktc; ++kt) t = fmaxf(t, sv[kt][i]);
                t = fmaxf(t, __shfl_xor(t, 1));
                t = fmaxf(t, __shfl_xor(t, 2));
                t = fmaxf(t, __shfl_xor(t, 4));
                t = fmaxf(t, __shfl_xor(t, 8));
                tm[i] = t;
            }
            float alpha[4];
#pragma unroll
            for (int i = 0; i < 4; ++i) {
                const float mn = fmaxf(mrow[i], tm[i]);
                alpha[i] = EXP2F(mrow[i] - mn);
                mrow[i] = mn;
            }
            const bool noop = (alpha[0] == 1.f) && (alpha[1] == 1.f) &&
                              (alpha[2] == 1.f) && (alpha[3] == 1.f);
            if (!__all(noop)) {
#pragma unroll
                for (int i = 0; i < 4; ++i) {
                    lrow_l[i] *= alpha[i];
#pragma unroll
                    for (int dt = 0; dt < 8; ++dt) acc_o[dt][i] *= alpha[i];
                }
            }
        }
        // ---- P = exp2(S - m), write to Ps, accumulate lane-local l ----
#pragma unroll
        for (int kt = 0; kt < 4; ++kt) {
            if (kt >= ktc) break;
#pragma unroll
            for (int i = 0; i < 4; ++i) {
                const float p = EXP2F(sv[kt][i] - mrow[i]);
                lrow_l[i] += p;
                Ps[w][(quad * 4 + i) * 72 + kt * 16 + ln] = f2bf(p);
            }
        }
        // ---- O += P V ----
        const int kbm = ktc >> 1;
        __builtin_amdgcn_s_setprio(1);
#pragma unroll
        for (int kb = 0; kb < 2; ++kb) {
            if (kb >= kbm) break;
            sfrag8 afr = *(const sfrag8*)&Ps[w][ln * 72 + kb * 32 + quad * 8];
#pragma unroll
            for (int dt = 0; dt < 8; ++dt) {
                sfrag8 bfr = *(const sfrag8*)&Vt[(dt * 16 + ln) * 72 + kb * 32 + quad * 8];
                acc_o[dt] = __builtin_amdgcn_mfma_f32_16x16x32_bf16(afr, bfr, acc_o[dt], 0, 0, 0);
            }
        }
        __builtin_amdgcn_s_setprio(0);
    }

    // ---- final l reduction (once) + write ctx ----
    float invl[4];
#pragma unroll
    for (int i = 0; i < 4; ++i) {
        float t = lrow_l[i];
        t += __shfl_xor(t, 1);
        t += __shfl_xor(t, 2);
        t += __shfl_xor(t, 4);
        t += __shfl_xor(t, 8);
        invl[i] = 1.0f / t;
    }
#pragma unroll
    for (int i = 0; i < 4; ++i) {
        u16* og = ctx + ((size_t)(qt * 64 + w * 16 + quad * 4 + i) * N_HEADS + head) * HEAD_DIM;
#pragma unroll
        for (int dt = 0; dt < 8; ++dt)
            og[dt * 16 + ln] = f2bf(acc_o[dt][i] * invl[i]);
    }
}

// ---------------------------------------------------------------------------
extern "C" void kernel_launch(void* const* d_in, const int* in_sizes, int n_in,
                              void* d_out, int out_size, void* d_ws, size_t ws_size,
                              hipStream_t stream) {
    (void)in_sizes; (void)n_in; (void)out_size;
    const float* x  = (const float*)d_in[0];
    const float* Wq = (const float*)d_in[2];
    const float* Wk = (const float*)d_in[3];
    const float* Wv = (const float*)d_in[4];
    const float* Wo = (const float*)d_in[5];
    float* out = (float*)d_out;
    char* ws = (char*)d_ws;
    const size_t MiB = 1024 * 1024;

    if (ws_size >= 88 * MiB) {
        // Layout: kbuf 0..4 | vtbuf 4..8 | qsl 8..24 | xb 24..40 |
        //         WqkvT 40..88 (6144 x 4096 bf16; reused for WoT)   [MiB]
        u16* kbuf  = (u16*)(ws);
        u16* vtbuf = (u16*)(ws + 4 * MiB);
        u16* qsl   = (u16*)(ws + 8 * MiB);
        u16* xb    = (u16*)(ws + 24 * MiB);
        u16* WqkvT = (u16*)(ws + 40 * MiB);

        convert_bf16<<<dim3(T_SEQ * D_MODEL / 8 / 256), 256, 0, stream>>>(
            x, xb, T_SEQ * D_MODEL / 8);
        // weights -> B^T bf16: rows 0..4095 Wq^T, 4096..5119 Wk^T, 5120..6143 Wv^T
        transpose_f32_bf16<<<dim3(64, 64), 256, 0, stream>>>(
            Wq, WqkvT, D_MODEL, N_HEADS * HEAD_DIM);
        transpose_f32_bf16<<<dim3(16, 64), 256, 0, stream>>>(
            Wk, WqkvT + (size_t)4096 * 4096, D_MODEL, K_HEADS * HEAD_DIM);
        transpose_f32_bf16<<<dim3(16, 64), 256, 0, stream>>>(
            Wv, WqkvT + (size_t)5120 * 4096, D_MODEL, K_HEADS * HEAD_DIM);

        // fused Q+K+V projection: one GEMM, routed epilogue (CMODE 4)
        gemm_bt<4><<<dim3(48, 16), 256, 0, stream>>>(
            xb, WqkvT, ws, T_SEQ, 6144, D_MODEL, 0);

        rope_kernel<<<dim3(K_HEADS, T_SEQ), 64, 0, stream>>>(kbuf, K_HEADS, 0);
        rope_kernel<<<dim3(N_HEADS, T_SEQ), 64, 0, stream>>>(qsl, N_HEADS, 0);

        // attention (ctx in-place in qsl)
        attn_mfma<<<dim3(N_HEADS, T_SEQ / 64), 256, 0, stream>>>(
            qsl, kbuf, vtbuf, qsl, 0);

        // output projection (WqkvT region reused for Wo^T; in-order stream)
        transpose_f32_bf16<<<dim3(64, 64), 256, 0, stream>>>(
            Wo, WqkvT, N_HEADS * HEAD_DIM, D_MODEL);
        gemm_bt<1><<<dim3(32, 16), 256, 0, stream>>>(
            qsl, WqkvT, out, T_SEQ, D_MODEL, N_HEADS * HEAD_DIM, D_MODEL);
        return;
    }

    // ------------------- fallback: previous verified path -------------------
    u16* kbuf  = (u16*)(ws);                 // [t][kvh][d]   4,194,304 B
    u16* vtbuf = (u16*)(ws + 4194304);       // [kvh*128+d][t] 4,194,304 B
    u16* qsl   = (u16*)(ws + 8388608);       // [t][h][d] slice

    int S = 8;
    if (ws_size >= (size_t)8388608 + 16777216)      S = 1;
    else if (ws_size >= (size_t)8388608 + 8388608)  S = 2;
    else if (ws_size >= (size_t)8388608 + 4194304)  S = 4;
    const int Ts = T_SEQ / S;

    gemm_any<0, 0><<<dim3(16, T_SEQ / 64), 256, 0, stream>>>(
        x, Wk, kbuf, T_SEQ, K_HEADS * HEAD_DIM, D_MODEL, K_HEADS * HEAD_DIM);
    gemm_any<0, 2><<<dim3(16, T_SEQ / 64), 256, 0, stream>>>(
        x, Wv, vtbuf, T_SEQ, K_HEADS * HEAD_DIM, D_MODEL, T_SEQ);
    rope_kernel<<<dim3(K_HEADS, T_SEQ), 64, 0, stream>>>(kbuf, K_HEADS, 0);

    for (int s = 0; s < S; ++s) {
        const int t0 = s * Ts;
        gemm_any<0, 0><<<dim3(64, Ts / 64), 256, 0, stream>>>(
            x + (size_t)t0 * D_MODEL, Wq, qsl, Ts, D_MODEL, D_MODEL, D_MODEL);
        rope_kernel<<<dim3(N_HEADS, Ts), 64, 0, stream>>>(qsl, N_HEADS, t0);
        // fallback attn: t0!=0 => qt remap still valid (nst from Tq0)
        attn_mfma<<<dim3(N_HEADS, Ts / 64), 256, 0, stream>>>(
            qsl, kbuf, vtbuf, qsl, t0);
        gemm_any<1, 1><<<dim3(64, Ts / 64), 256, 0, stream>>>(
            qsl, Wo, out + (size_t)t0 * D_MODEL, Ts, D_MODEL, N_HEADS * HEAD_DIM, D_MODEL);
    }
}

// Round 6
// 524.047 us; speedup vs baseline: 1.4075x; 1.0489x over previous
//
#include <hip/hip_runtime.h>
#include <hip/hip_bf16.h>

// Problem constants
#define T_SEQ 2048
#define D_MODEL 4096
#define N_HEADS 32
#define K_HEADS 8
#define HEAD_DIM 128

typedef unsigned short u16;
typedef short sfrag8 __attribute__((ext_vector_type(8)));   // 8 bf16 (4 VGPRs)
typedef float ffrag4 __attribute__((ext_vector_type(4)));   // 4 f32 acc

#if defined(__has_builtin)
#  if __has_builtin(__builtin_amdgcn_exp2f)
#    define EXP2F(x) __builtin_amdgcn_exp2f(x)
#  else
#    define EXP2F(x) exp2f(x)
#  endif
#else
#  define EXP2F(x) exp2f(x)
#endif

// 1/sqrt(128) * log2(e): softmax in exp2 domain.
#define QSCALE_LOG2E 0.12751744900463627f
// -log2(500000)/64 for rope inv_freq via exp2
#define NEG_L2_THETA_64 (-0.29580575889569f)

__device__ __forceinline__ float bf2f(u16 u) {
    return __uint_as_float(((unsigned int)u) << 16);
}
__device__ __forceinline__ u16 f2bf(float f) {
    unsigned int x = __float_as_uint(f);
    unsigned int r = (x + 0x7fffu + ((x >> 16) & 1u)) >> 16;  // RTNE
    return (u16)r;
}
__device__ __forceinline__ uint4 pack8(const float4 a, const float4 b) {
    uint4 r;
    r.x = (unsigned)f2bf(a.x) | ((unsigned)f2bf(a.y) << 16);
    r.y = (unsigned)f2bf(a.z) | ((unsigned)f2bf(a.w) << 16);
    r.z = (unsigned)f2bf(b.x) | ((unsigned)f2bf(b.y) << 16);
    r.w = (unsigned)f2bf(b.z) | ((unsigned)f2bf(b.w) << 16);
    return r;
}

// async global->LDS, 16B per lane.
__device__ __forceinline__ void gload_lds16(const u16* g, u16* l) {
    __builtin_amdgcn_global_load_lds(
        (const __attribute__((address_space(1))) void*)g,
        (__attribute__((address_space(3))) void*)l, 16, 0, 0);
}

// ---------------------------------------------------------------------------
// Prep: f32 -> bf16 elementwise convert (8 elems / thread).
// ---------------------------------------------------------------------------
__global__ __launch_bounds__(256) void convert_bf16(
    const float* __restrict__ X, u16* __restrict__ Y, int n8)
{
    const int i = blockIdx.x * 256 + threadIdx.x;
    if (i < n8) {
        float4 a = ((const float4*)X)[(size_t)i * 2];
        float4 b = ((const float4*)X)[(size_t)i * 2 + 1];
        ((uint4*)Y)[i] = pack8(a, b);
    }
}

// ---------------------------------------------------------------------------
// Prep: transpose + convert. W (R x C) f32 row-major -> WT (C x R) bf16.
// ---------------------------------------------------------------------------
__global__ __launch_bounds__(256) void transpose_f32_bf16(
    const float* __restrict__ W, u16* __restrict__ WT, int R, int C)
{
    __shared__ float Ts[64][65];
    const int t = threadIdx.x;
    const int c0 = blockIdx.x * 64, r0 = blockIdx.y * 64;
    const int rl = t >> 4, cl = (t & 15) * 4;
#pragma unroll
    for (int p = 0; p < 4; ++p) {
        const int r = p * 16 + rl;
        float4 v = *(const float4*)(W + (size_t)(r0 + r) * C + c0 + cl);
        Ts[r][cl] = v.x; Ts[r][cl + 1] = v.y; Ts[r][cl + 2] = v.z; Ts[r][cl + 3] = v.w;
    }
    __syncthreads();
    const int nl = t >> 2, k4 = (t & 3) * 16;
    u16 tmp[16];
#pragma unroll
    for (int j = 0; j < 16; ++j) tmp[j] = f2bf(Ts[k4 + j][nl]);
    u16* dst = WT + (size_t)(c0 + nl) * R + r0 + k4;
    *(uint4*)(dst) = *(uint4*)&tmp[0];
    *(uint4*)(dst + 8) = *(uint4*)&tmp[8];
}

// ---------------------------------------------------------------------------
// m97-structure GEMM: C(M x Nb) = A(M x Kd) * BT(Nb x Kd)^T, all bf16 in.
// Tile 128x128, BK=64, 4 waves. XCD-aware bijective block swizzle (grid size
// must be a multiple of 8 -- true for all launches here).
// CMODE: 0 bf16 natural (ldc), 1 f32 (ldc),
//        4 fused QKV epilogue WITH FUSED ROPE: Cp = workspace base.
//          gcol < 4096          -> qsl  (ws+8MiB)  [t][4096] bf16, roped
//          4096 <= gcol < 5120  -> kbuf (ws+0)     [t][1024] bf16, roped
//          gcol >= 5120         -> vtbuf(ws+4MiB)  [kvd][T_SEQ] bf16 (transp.)
//        Rope path: each Q/K block is exactly one 128-dim head (n0 is
//        128-aligned), so the (d, d+64) pair lives in-block. Stage acc as
//        bf16 in SmemAll[128][128] (reuses the staging LDS after the final
//        K-loop barrier), barrier, re-read pairs, rotate, store.
// ---------------------------------------------------------------------------
template <int CMODE>
__global__ __launch_bounds__(256) void gemm_bt(
    const u16* __restrict__ A, const u16* __restrict__ BT,
    void* __restrict__ Cp, int M, int Nb, int Kd, int ldc)
{
    __shared__ __align__(16) u16 SmemAll[2 * 128 * 64];   // As | Bs (contiguous)
    u16* As = SmemAll;
    u16* Bs = SmemAll + 128 * 64;

    const int tid = threadIdx.x;
    const int lane = tid & 63;
    const int w = tid >> 6;
    const int wm = w >> 1, wn = w & 1;
    const int ln = lane & 15, quad = lane >> 4;

    // XCD-aware swizzle: contiguous chunk of blocks per XCD (bijective,
    // nwg % 8 == 0 for all launches of this kernel).
    int wid = blockIdx.y * gridDim.x + blockIdx.x;
    const int nwg = gridDim.x * gridDim.y;
    const int cpx = nwg >> 3;
    wid = (wid & 7) * cpx + (wid >> 3);
    const int bx = wid % gridDim.x;
    const int by = wid / gridDim.x;

    const int m0 = by * 128, n0 = bx * 128;

    size_t aoff[4], boff[4];
#pragma unroll
    for (int i = 0; i < 4; ++i) {
        const int row = (i * 4 + w) * 8 + (lane >> 3);
        const int cg = (lane & 7) ^ (lane >> 3);
        aoff[i] = (size_t)(m0 + row) * Kd + cg * 8;
        boff[i] = (size_t)(n0 + row) * Kd + cg * 8;
    }

    ffrag4 acc[4][4];
#pragma unroll
    for (int mi = 0; mi < 4; ++mi)
#pragma unroll
        for (int ni = 0; ni < 4; ++ni) acc[mi][ni] = (ffrag4){0.f, 0.f, 0.f, 0.f};

    for (int k0 = 0; k0 < Kd; k0 += 64) {
#pragma unroll
        for (int i = 0; i < 4; ++i) {
            gload_lds16(A + aoff[i] + k0, &As[(i * 4 + w) * 512]);
            gload_lds16(BT + boff[i] + k0, &Bs[(i * 4 + w) * 512]);
        }
        __syncthreads();

#pragma unroll
        for (int kk = 0; kk < 2; ++kk) {
            sfrag8 af[4], bfv[4];
#pragma unroll
            for (int mi = 0; mi < 4; ++mi) {
                const int row = wm * 64 + mi * 16 + ln;
                const int pc = ((kk * 4) | quad) ^ (ln & 7);
                af[mi] = *(const sfrag8*)&As[row * 64 + pc * 8];
            }
#pragma unroll
            for (int ni = 0; ni < 4; ++ni) {
                const int row = wn * 64 + ni * 16 + ln;
                const int pc = ((kk * 4) | quad) ^ (ln & 7);
                bfv[ni] = *(const sfrag8*)&Bs[row * 64 + pc * 8];
            }
#pragma unroll
            for (int mi = 0; mi < 4; ++mi)
#pragma unroll
                for (int ni = 0; ni < 4; ++ni)
                    acc[mi][ni] = __builtin_amdgcn_mfma_f32_16x16x32_bf16(
                        af[mi], bfv[ni], acc[mi][ni], 0, 0, 0);
        }
        __syncthreads();
    }

    if constexpr (CMODE == 4) {
        u16* base = (u16*)Cp;   // workspace base
        if (n0 < 5120) {
            // ---- rope path (Q or K head). Stage acc tile as bf16. ----
#pragma unroll
            for (int mi = 0; mi < 4; ++mi)
#pragma unroll
                for (int ni = 0; ni < 4; ++ni) {
                    const int colL = wn * 64 + ni * 16 + ln;
#pragma unroll
                    for (int i = 0; i < 4; ++i) {
                        const int rowL = wm * 64 + mi * 16 + quad * 4 + i;
                        SmemAll[rowL * 128 + colL] = f2bf(acc[mi][ni][i]);
                    }
                }
            __syncthreads();
            // per-thread inv_freq for its 4 ni values (fi independent of wn)
            float invf[4];
#pragma unroll
            for (int ni = 0; ni < 4; ++ni)
                invf[ni] = EXP2F((float)(ni * 16 + ln) * NEG_L2_THETA_64);
#pragma unroll
            for (int mi = 0; mi < 4; ++mi)
#pragma unroll
                for (int ni = 0; ni < 4; ++ni) {
                    const int colL = wn * 64 + ni * 16 + ln;
                    const int fi = colL & 63;
                    const int gcol = n0 + colL;
#pragma unroll
                    for (int i = 0; i < 4; ++i) {
                        const int rowL = wm * 64 + mi * 16 + quad * 4 + i;
                        const int grow = m0 + rowL;
                        const float x1 = bf2f(SmemAll[rowL * 128 + fi]);
                        const float x2 = bf2f(SmemAll[rowL * 128 + fi + 64]);
                        const float ang = (float)grow * invf[ni];
                        const float cw = cosf(ang);
                        const float sw = sinf(ang);
                        const float o = (wn == 0) ? (x1 * cw - x2 * sw)
                                                  : (x2 * cw + x1 * sw);
                        const u16 v = f2bf(o);
                        if (gcol < 4096) {          // qsl at ws+8MiB
                            base[4194304u + (size_t)grow * 4096 + gcol] = v;
                        } else {                    // kbuf at ws+0
                            base[(size_t)grow * 1024 + (gcol - 4096)] = v;
                        }
                    }
                }
        } else {
            // ---- V region: direct transposed store, no rope ----
#pragma unroll
            for (int mi = 0; mi < 4; ++mi)
#pragma unroll
                for (int ni = 0; ni < 4; ++ni) {
                    const int gcol = n0 + wn * 64 + ni * 16 + ln;
#pragma unroll
                    for (int i = 0; i < 4; ++i) {
                        const int grow = m0 + wm * 64 + mi * 16 + quad * 4 + i;
                        base[2097152u + (size_t)(gcol - 5120) * T_SEQ + grow] =
                            f2bf(acc[mi][ni][i]);
                    }
                }
        }
        return;
    }

#pragma unroll
    for (int mi = 0; mi < 4; ++mi) {
#pragma unroll
        for (int ni = 0; ni < 4; ++ni) {
            const int gcol = n0 + wn * 64 + ni * 16 + ln;
#pragma unroll
            for (int i = 0; i < 4; ++i) {
                const int grow = m0 + wm * 64 + mi * 16 + quad * 4 + i;
                if constexpr (CMODE == 1) {
                    ((float*)Cp)[(size_t)grow * ldc + gcol] = acc[mi][ni][i];
                } else {
                    ((u16*)Cp)[(size_t)grow * ldc + gcol] = f2bf(acc[mi][ni][i]);
                }
            }
        }
    }
}

// ---------------------------------------------------------------------------
// OLD GEMM (fallback path only).
// ---------------------------------------------------------------------------
template <int AMODE, int CMODE>
__global__ __launch_bounds__(256) void gemm_any(
    const void* __restrict__ Ap, const float* __restrict__ B, void* __restrict__ Cp,
    int M, int Nb, int Kd, int ldc)
{
    __shared__ __align__(16) u16 As[64 * 64];
    __shared__ __align__(16) u16 Bs[64 * 72];

    const int tid = threadIdx.x;
    const int n0 = blockIdx.x * 64, m0 = blockIdx.y * 64;

    const int lr = tid >> 3;
    const int cc8 = tid & 7;
    const int sw = ((cc8 ^ (lr & 7)) * 8);
    const int dstA0 = lr * 64 + sw;
    const int dstA1 = (lr + 32) * 64 + sw;
    const size_t arow0 = (size_t)(m0 + lr) * Kd;
    const size_t arow1 = (size_t)(m0 + lr + 32) * Kd;

    const int kr = tid >> 2;
    const int ncb = (tid & 3) * 16;

    const int lane = tid & 63;
    const int w = tid >> 6;
    const int col16 = lane & 15;
    const int quad = lane >> 4;
    const int swl = lane & 7;
    const int mrow = w * 16 + col16;

    ffrag4 acc[4];
#pragma unroll
    for (int j = 0; j < 4; ++j) acc[j] = (ffrag4){0.f, 0.f, 0.f, 0.f};

    for (int k0 = 0; k0 < Kd; k0 += 64) {
        if constexpr (AMODE == 1) {
            const u16* Af = (const u16*)Ap;
            uint4 va0 = *(const uint4*)(Af + arow0 + k0 + cc8 * 8);
            uint4 va1 = *(const uint4*)(Af + arow1 + k0 + cc8 * 8);
            *(uint4*)&As[dstA0] = va0;
            *(uint4*)&As[dstA1] = va1;
        } else {
            const float* Af = (const float*)Ap;
            float4 a00 = *(const float4*)(Af + arow0 + k0 + cc8 * 8);
            float4 a01 = *(const float4*)(Af + arow0 + k0 + cc8 * 8 + 4);
            float4 a10 = *(const float4*)(Af + arow1 + k0 + cc8 * 8);
            float4 a11 = *(const float4*)(Af + arow1 + k0 + cc8 * 8 + 4);
            *(uint4*)&As[dstA0] = pack8(a00, a01);
            *(uint4*)&As[dstA1] = pack8(a10, a11);
        }
        {
            const float* bp = B + (size_t)(k0 + kr) * Nb + n0 + ncb;
            float4 b0 = *(const float4*)(bp);
            float4 b1 = *(const float4*)(bp + 4);
            float4 b2 = *(const float4*)(bp + 8);
            float4 b3 = *(const float4*)(bp + 12);
            u16 tmp[16];
            tmp[0] = f2bf(b0.x); tmp[1] = f2bf(b0.y); tmp[2] = f2bf(b0.z); tmp[3] = f2bf(b0.w);
            tmp[4] = f2bf(b1.x); tmp[5] = f2bf(b1.y); tmp[6] = f2bf(b1.z); tmp[7] = f2bf(b1.w);
            tmp[8] = f2bf(b2.x); tmp[9] = f2bf(b2.y); tmp[10] = f2bf(b2.z); tmp[11] = f2bf(b2.w);
            tmp[12] = f2bf(b3.x); tmp[13] = f2bf(b3.y); tmp[14] = f2bf(b3.z); tmp[15] = f2bf(b3.w);
#pragma unroll
            for (int e = 0; e < 16; ++e)
                Bs[(ncb + e) * 72 + kr] = tmp[e];
        }
        __syncthreads();
#pragma unroll
        for (int c = 0; c < 2; ++c) {
            const int cc = c * 4 + quad;
            const int koffA = (cc ^ swl) * 8;
            sfrag8 af = *(const sfrag8*)&As[mrow * 64 + koffA];
#pragma unroll
            for (int j = 0; j < 4; ++j) {
                sfrag8 bfv = *(const sfrag8*)&Bs[(j * 16 + col16) * 72 + cc * 8];
                acc[j] = __builtin_amdgcn_mfma_f32_16x16x32_bf16(af, bfv, acc[j], 0, 0, 0);
            }
        }
        __syncthreads();
    }

#pragma unroll
    for (int j = 0; j < 4; ++j) {
        const int gcol = n0 + j * 16 + col16;
#pragma unroll
        for (int i = 0; i < 4; ++i) {
            const int grow = m0 + w * 16 + quad * 4 + i;
            if constexpr (CMODE == 1) {
                ((float*)Cp)[(size_t)grow * ldc + gcol] = acc[j][i];
            } else if constexpr (CMODE == 2) {
                ((u16*)Cp)[(size_t)gcol * ldc + grow] = f2bf(acc[j][i]);
            } else {
                ((u16*)Cp)[(size_t)grow * ldc + gcol] = f2bf(acc[j][i]);
            }
        }
    }
}

// ---------------------------------------------------------------------------
// RoPE in-place on (rows x nheads x HEAD_DIM) bf16. grid (nheads, rows).
// (fallback path only)
// ---------------------------------------------------------------------------
__global__ __launch_bounds__(64) void rope_kernel(
    u16* __restrict__ buf, int nheads, int t0)
{
    const int h = blockIdx.x;
    const int t = blockIdx.y;
    u16* rowp = buf + ((size_t)t * nheads + h) * HEAD_DIM;
    const int i = threadIdx.x;  // 0..63
    const float p = (float)(t0 + t);
    const float inv = expf(-((float)i * (1.0f / 64.0f)) * 13.122363377404329f);
    const float ang = p * inv;
    const float c = cosf(ang);
    const float s = sinf(ang);
    const float x1 = bf2f(rowp[i]);
    const float x2 = bf2f(rowp[i + 64]);
    rowp[i] = f2bf(x1 * c - x2 * s);
    rowp[i + 64] = f2bf(x2 * c + x1 * s);
}

// ---------------------------------------------------------------------------
// MFMA flash attention, causal, GQA. grid (N_HEADS, Ts/64), block 256 (4
// waves). Round-5 verified structure (defer-max THR=8, exp2 domain,
// lane-local l, setprio, longest-first qt remap).
// ---------------------------------------------------------------------------
__global__ __launch_bounds__(256) void attn_mfma(
    const u16* q, const u16* __restrict__ k,
    const u16* __restrict__ vt, u16* ctx, int t0)
{
    __shared__ __align__(16) u16 Kt[64 * 136];      // [key][d], pad 8
    __shared__ __align__(16) u16 Vt[128 * 72];      // [d][key], pad 8
    __shared__ __align__(16) u16 Ps[4][16 * 72];    // per-wave [q][key], pad 8

    const int head = blockIdx.x;
    const int qt = gridDim.y - 1 - blockIdx.y;      // longest-first dispatch
    const int kvh = head >> 2;
    const int tid = threadIdx.x;
    const int lane = tid & 63;
    const int w = tid >> 6;          // wave id
    const int ln = lane & 15;
    const int quad = lane >> 4;

    // staging assignments
    const int kr = tid >> 2;         // 0..63  (K rows)
    const int c4 = (tid & 3) * 32;   // d-chunk for K
    const int vd = tid >> 1;         // 0..127 (Vt rows = dims)
    const int vh = (tid & 1) * 32;   // key-chunk for Vt

    // Q fragments: A[m=ln][k=kk*32+quad*8+j]  (Q already roped)
    const int qrow_loc = qt * 64 + w * 16 + ln;
    sfrag8 qf[4];
    {
        const u16* qg = q + ((size_t)qrow_loc * N_HEADS + head) * HEAD_DIM;
#pragma unroll
        for (int kk = 0; kk < 4; ++kk)
            qf[kk] = *(const sfrag8*)(qg + kk * 32 + quad * 8);
    }

    ffrag4 acc_o[8];
#pragma unroll
    for (int dt = 0; dt < 8; ++dt) acc_o[dt] = (ffrag4){0.f, 0.f, 0.f, 0.f};
    float mrow[4] = {-INFINITY, -INFINITY, -INFINITY, -INFINITY};
    float lrow_l[4] = {0.f, 0.f, 0.f, 0.f};   // lane-local partial sums

    const int Tq0 = t0 + qt * 64;           // absolute base of q tile
    const int nst = Tq0 / 64 + 1;           // KV tiles incl. diagonal
    const int qabs_base = Tq0 + w * 16 + quad * 4;  // + i = abs q row

    for (int st = 0; st < nst; ++st) {
        const int kv0 = st * 64;
        const bool diag = (st == nst - 1);

        __syncthreads();   // prev tile compute done: LDS safe to overwrite
        // stage K tile: Kt[key][d]
        {
            const u16* kg = k + ((size_t)(kv0 + kr) * K_HEADS + kvh) * HEAD_DIM + c4;
            u16* kd = &Kt[kr * 136 + c4];
#pragma unroll
            for (int j = 0; j < 4; ++j)
                *(uint4*)(kd + j * 8) = *(const uint4*)(kg + j * 8);
        }
        // stage V tile transposed: Vt[d][key]
        {
            const u16* vg = vt + ((size_t)(kvh * 128 + vd)) * T_SEQ + kv0 + vh;
            u16* vdst = &Vt[vd * 72 + vh];
#pragma unroll
            for (int j = 0; j < 4; ++j)
                *(uint4*)(vdst + j * 8) = *(const uint4*)(vg + j * 8);
        }
        __syncthreads();   // tiles ready

        const int ktc = diag ? ((w < 2) ? 2 : 4) : 4;   // key subtiles computed
        // ---- S = Q K^T ----
        ffrag4 sacc[4];
        __builtin_amdgcn_s_setprio(1);
#pragma unroll
        for (int kt = 0; kt < 4; ++kt) {
            if (kt >= ktc) break;
            sacc[kt] = (ffrag4){0.f, 0.f, 0.f, 0.f};
#pragma unroll
            for (int kk = 0; kk < 4; ++kk) {
                sfrag8 bfr = *(const sfrag8*)&Kt[(kt * 16 + ln) * 136 + kk * 32 + quad * 8];
                sacc[kt] = __builtin_amdgcn_mfma_f32_16x16x32_bf16(qf[kk], bfr, sacc[kt], 0, 0, 0);
            }
        }
        __builtin_amdgcn_s_setprio(0);
        // ---- scale (exp2 domain) + causal mask ----
        float sv[4][4];
#pragma unroll
        for (int kt = 0; kt < 4; ++kt) {
            if (kt >= ktc) break;
            const int key_abs = kv0 + kt * 16 + ln;
#pragma unroll
            for (int i = 0; i < 4; ++i) {
                float s = sacc[kt][i] * QSCALE_LOG2E;
                if (diag && key_abs > qabs_base + i) s = -INFINITY;
                sv[kt][i] = s;
            }
        }
        // ---- defer-max (T13): only reduce/rescale when max grew > THR ----
        bool grew = false;
#pragma unroll
        for (int kt = 0; kt < 4; ++kt) {
            if (kt >= ktc) break;
#pragma unroll
            for (int i = 0; i < 4; ++i)
                grew |= (sv[kt][i] > mrow[i] + 8.0f);
        }
        if (__any(grew)) {
            // full path: tile row max (across kt and 16 lanes)
            float tm[4];
#pragma unroll
            for (int i = 0; i < 4; ++i) {
                float t = sv[0][i];
                for (int kt = 1; kt < ktc; ++kt) t = fmaxf(t, sv[kt][i]);
                t = fmaxf(t, __shfl_xor(t, 1));
                t = fmaxf(t, __shfl_xor(t, 2));
                t = fmaxf(t, __shfl_xor(t, 4));
                t = fmaxf(t, __shfl_xor(t, 8));
                tm[i] = t;
            }
            float alpha[4];
#pragma unroll
            for (int i = 0; i < 4; ++i) {
                const float mn = fmaxf(mrow[i], tm[i]);
                alpha[i] = EXP2F(mrow[i] - mn);
                mrow[i] = mn;
            }
            const bool noop = (alpha[0] == 1.f) && (alpha[1] == 1.f) &&
                              (alpha[2] == 1.f) && (alpha[3] == 1.f);
            if (!__all(noop)) {
#pragma unroll
                for (int i = 0; i < 4; ++i) {
                    lrow_l[i] *= alpha[i];
#pragma unroll
                    for (int dt = 0; dt < 8; ++dt) acc_o[dt][i] *= alpha[i];
                }
            }
        }
        // ---- P = exp2(S - m), write to Ps, accumulate lane-local l ----
#pragma unroll
        for (int kt = 0; kt < 4; ++kt) {
            if (kt >= ktc) break;
#pragma unroll
            for (int i = 0; i < 4; ++i) {
                const float p = EXP2F(sv[kt][i] - mrow[i]);
                lrow_l[i] += p;
                Ps[w][(quad * 4 + i) * 72 + kt * 16 + ln] = f2bf(p);
            }
        }
        // ---- O += P V ----
        const int kbm = ktc >> 1;
        __builtin_amdgcn_s_setprio(1);
#pragma unroll
        for (int kb = 0; kb < 2; ++kb) {
            if (kb >= kbm) break;
            sfrag8 afr = *(const sfrag8*)&Ps[w][ln * 72 + kb * 32 + quad * 8];
#pragma unroll
            for (int dt = 0; dt < 8; ++dt) {
                sfrag8 bfr = *(const sfrag8*)&Vt[(dt * 16 + ln) * 72 + kb * 32 + quad * 8];
                acc_o[dt] = __builtin_amdgcn_mfma_f32_16x16x32_bf16(afr, bfr, acc_o[dt], 0, 0, 0);
            }
        }
        __builtin_amdgcn_s_setprio(0);
    }

    // ---- final l reduction (once) + write ctx ----
    float invl[4];
#pragma unroll
    for (int i = 0; i < 4; ++i) {
        float t = lrow_l[i];
        t += __shfl_xor(t, 1);
        t += __shfl_xor(t, 2);
        t += __shfl_xor(t, 4);
        t += __shfl_xor(t, 8);
        invl[i] = 1.0f / t;
    }
#pragma unroll
    for (int i = 0; i < 4; ++i) {
        u16* og = ctx + ((size_t)(qt * 64 + w * 16 + quad * 4 + i) * N_HEADS + head) * HEAD_DIM;
#pragma unroll
        for (int dt = 0; dt < 8; ++dt)
            og[dt * 16 + ln] = f2bf(acc_o[dt][i] * invl[i]);
    }
}

// ---------------------------------------------------------------------------
extern "C" void kernel_launch(void* const* d_in, const int* in_sizes, int n_in,
                              void* d_out, int out_size, void* d_ws, size_t ws_size,
                              hipStream_t stream) {
    (void)in_sizes; (void)n_in; (void)out_size;
    const float* x  = (const float*)d_in[0];
    const float* Wq = (const float*)d_in[2];
    const float* Wk = (const float*)d_in[3];
    const float* Wv = (const float*)d_in[4];
    const float* Wo = (const float*)d_in[5];
    float* out = (float*)d_out;
    char* ws = (char*)d_ws;
    const size_t MiB = 1024 * 1024;

    if (ws_size >= 88 * MiB) {
        // Layout: kbuf 0..4 | vtbuf 4..8 | qsl 8..24 | xb 24..40 |
        //         WqkvT 40..88 (6144 x 4096 bf16; reused for WoT)   [MiB]
        u16* kbuf  = (u16*)(ws);
        u16* vtbuf = (u16*)(ws + 4 * MiB);
        u16* qsl   = (u16*)(ws + 8 * MiB);
        u16* xb    = (u16*)(ws + 24 * MiB);
        u16* WqkvT = (u16*)(ws + 40 * MiB);

        convert_bf16<<<dim3(T_SEQ * D_MODEL / 8 / 256), 256, 0, stream>>>(
            x, xb, T_SEQ * D_MODEL / 8);
        // weights -> B^T bf16: rows 0..4095 Wq^T, 4096..5119 Wk^T, 5120..6143 Wv^T
        transpose_f32_bf16<<<dim3(64, 64), 256, 0, stream>>>(
            Wq, WqkvT, D_MODEL, N_HEADS * HEAD_DIM);
        transpose_f32_bf16<<<dim3(16, 64), 256, 0, stream>>>(
            Wk, WqkvT + (size_t)4096 * 4096, D_MODEL, K_HEADS * HEAD_DIM);
        transpose_f32_bf16<<<dim3(16, 64), 256, 0, stream>>>(
            Wv, WqkvT + (size_t)5120 * 4096, D_MODEL, K_HEADS * HEAD_DIM);

        // fused Q+K+V projection + RoPE: one GEMM, routed epilogue (CMODE 4)
        gemm_bt<4><<<dim3(48, 16), 256, 0, stream>>>(
            xb, WqkvT, ws, T_SEQ, 6144, D_MODEL, 0);

        // attention (ctx in-place in qsl)
        attn_mfma<<<dim3(N_HEADS, T_SEQ / 64), 256, 0, stream>>>(
            qsl, kbuf, vtbuf, qsl, 0);

        // output projection (WqkvT region reused for Wo^T; in-order stream)
        transpose_f32_bf16<<<dim3(64, 64), 256, 0, stream>>>(
            Wo, WqkvT, N_HEADS * HEAD_DIM, D_MODEL);
        gemm_bt<1><<<dim3(32, 16), 256, 0, stream>>>(
            qsl, WqkvT, out, T_SEQ, D_MODEL, N_HEADS * HEAD_DIM, D_MODEL);
        return;
    }

    // ------------------- fallback: previous verified path -------------------
    u16* kbuf  = (u16*)(ws);                 // [t][kvh][d]   4,194,304 B
    u16* vtbuf = (u16*)(ws + 4194304);       // [kvh*128+d][t] 4,194,304 B
    u16* qsl   = (u16*)(ws + 8388608);       // [t][h][d] slice

    int S = 8;
    if (ws_size >= (size_t)8388608 + 16777216)      S = 1;
    else if (ws_size >= (size_t)8388608 + 8388608)  S = 2;
    else if (ws_size >= (size_t)8388608 + 4194304)  S = 4;
    const int Ts = T_SEQ / S;

    gemm_any<0, 0><<<dim3(16, T_SEQ / 64), 256, 0, stream>>>(
        x, Wk, kbuf, T_SEQ, K_HEADS * HEAD_DIM, D_MODEL, K_HEADS * HEAD_DIM);
    gemm_any<0, 2><<<dim3(16, T_SEQ / 64), 256, 0, stream>>>(
        x, Wv, vtbuf, T_SEQ, K_HEADS * HEAD_DIM, D_MODEL, T_SEQ);
    rope_kernel<<<dim3(K_HEADS, T_SEQ), 64, 0, stream>>>(kbuf, K_HEADS, 0);

    for (int s = 0; s < S; ++s) {
        const int t0 = s * Ts;
        gemm_any<0, 0><<<dim3(64, Ts / 64), 256, 0, stream>>>(
            x + (size_t)t0 * D_MODEL, Wq, qsl, Ts, D_MODEL, D_MODEL, D_MODEL);
        rope_kernel<<<dim3(N_HEADS, Ts), 64, 0, stream>>>(qsl, N_HEADS, t0);
        attn_mfma<<<dim3(N_HEADS, Ts / 64), 256, 0, stream>>>(
            qsl, kbuf, vtbuf, qsl, t0);
        gemm_any<1, 1><<<dim3(64, Ts / 64), 256, 0, stream>>>(
            qsl, Wo, out + (size_t)t0 * D_MODEL, Ts, D_MODEL, N_HEADS * HEAD_DIM, D_MODEL);
    }
}

// Round 7
// 508.930 us; speedup vs baseline: 1.4493x; 1.0297x over previous
//
#include <hip/hip_runtime.h>
#include <hip/hip_bf16.h>

// Problem constants
#define T_SEQ 2048
#define D_MODEL 4096
#define N_HEADS 32
#define K_HEADS 8
#define HEAD_DIM 128

typedef unsigned short u16;
typedef short sfrag8 __attribute__((ext_vector_type(8)));   // 8 bf16 (4 VGPRs)
typedef float ffrag4 __attribute__((ext_vector_type(4)));   // 4 f32 acc

#if defined(__has_builtin)
#  if __has_builtin(__builtin_amdgcn_exp2f)
#    define EXP2F(x) __builtin_amdgcn_exp2f(x)
#  else
#    define EXP2F(x) exp2f(x)
#  endif
#else
#  define EXP2F(x) exp2f(x)
#endif

// 1/sqrt(128) * log2(e): softmax in exp2 domain.
#define QSCALE_LOG2E 0.12751744900463627f
// -log2(500000)/64 for rope inv_freq via exp2
#define NEG_L2_THETA_64 (-0.29580575889569f)

__device__ __forceinline__ float bf2f(u16 u) {
    return __uint_as_float(((unsigned int)u) << 16);
}
__device__ __forceinline__ u16 f2bf(float f) {
    unsigned int x = __float_as_uint(f);
    unsigned int r = (x + 0x7fffu + ((x >> 16) & 1u)) >> 16;  // RTNE
    return (u16)r;
}
__device__ __forceinline__ uint4 pack8(const float4 a, const float4 b) {
    uint4 r;
    r.x = (unsigned)f2bf(a.x) | ((unsigned)f2bf(a.y) << 16);
    r.y = (unsigned)f2bf(a.z) | ((unsigned)f2bf(a.w) << 16);
    r.z = (unsigned)f2bf(b.x) | ((unsigned)f2bf(b.y) << 16);
    r.w = (unsigned)f2bf(b.z) | ((unsigned)f2bf(b.w) << 16);
    return r;
}

// async global->LDS, 16B per lane. LDS base wave-uniform; global addr per-lane.
__device__ __forceinline__ void gload_lds16(const u16* g, u16* l) {
    __builtin_amdgcn_global_load_lds(
        (const __attribute__((address_space(1))) void*)g,
        (__attribute__((address_space(3))) void*)l, 16, 0, 0);
}

// ---------------------------------------------------------------------------
// Prep: f32 -> bf16 elementwise convert (8 elems / thread).
// ---------------------------------------------------------------------------
__global__ __launch_bounds__(256) void convert_bf16(
    const float* __restrict__ X, u16* __restrict__ Y, int n8)
{
    const int i = blockIdx.x * 256 + threadIdx.x;
    if (i < n8) {
        float4 a = ((const float4*)X)[(size_t)i * 2];
        float4 b = ((const float4*)X)[(size_t)i * 2 + 1];
        ((uint4*)Y)[i] = pack8(a, b);
    }
}

// ---------------------------------------------------------------------------
// Prep: transpose + convert. W (R x C) f32 row-major -> WT (C x R) bf16.
// ---------------------------------------------------------------------------
__global__ __launch_bounds__(256) void transpose_f32_bf16(
    const float* __restrict__ W, u16* __restrict__ WT, int R, int C)
{
    __shared__ float Ts[64][65];
    const int t = threadIdx.x;
    const int c0 = blockIdx.x * 64, r0 = blockIdx.y * 64;
    const int rl = t >> 4, cl = (t & 15) * 4;
#pragma unroll
    for (int p = 0; p < 4; ++p) {
        const int r = p * 16 + rl;
        float4 v = *(const float4*)(W + (size_t)(r0 + r) * C + c0 + cl);
        Ts[r][cl] = v.x; Ts[r][cl + 1] = v.y; Ts[r][cl + 2] = v.z; Ts[r][cl + 3] = v.w;
    }
    __syncthreads();
    const int nl = t >> 2, k4 = (t & 3) * 16;
    u16 tmp[16];
#pragma unroll
    for (int j = 0; j < 16; ++j) tmp[j] = f2bf(Ts[k4 + j][nl]);
    u16* dst = WT + (size_t)(c0 + nl) * R + r0 + k4;
    *(uint4*)(dst) = *(uint4*)&tmp[0];
    *(uint4*)(dst + 8) = *(uint4*)&tmp[8];
}

// ---------------------------------------------------------------------------
// m97-structure GEMM: C(M x Nb) = A(M x Kd) * BT(Nb x Kd)^T, all bf16 in.
// Tile 128x128, BK=64, 4 waves. XCD-aware bijective block swizzle.
// CMODE: 0 bf16 natural (ldc), 1 f32 (ldc),
//        4 fused QKV epilogue WITH FUSED ROPE (see round-6 comments).
// ---------------------------------------------------------------------------
template <int CMODE>
__global__ __launch_bounds__(256) void gemm_bt(
    const u16* __restrict__ A, const u16* __restrict__ BT,
    void* __restrict__ Cp, int M, int Nb, int Kd, int ldc)
{
    __shared__ __align__(16) u16 SmemAll[2 * 128 * 64];   // As | Bs (contiguous)
    u16* As = SmemAll;
    u16* Bs = SmemAll + 128 * 64;

    const int tid = threadIdx.x;
    const int lane = tid & 63;
    const int w = tid >> 6;
    const int wm = w >> 1, wn = w & 1;
    const int ln = lane & 15, quad = lane >> 4;

    int wid = blockIdx.y * gridDim.x + blockIdx.x;
    const int nwg = gridDim.x * gridDim.y;
    const int cpx = nwg >> 3;
    wid = (wid & 7) * cpx + (wid >> 3);
    const int bx = wid % gridDim.x;
    const int by = wid / gridDim.x;

    const int m0 = by * 128, n0 = bx * 128;

    size_t aoff[4], boff[4];
#pragma unroll
    for (int i = 0; i < 4; ++i) {
        const int row = (i * 4 + w) * 8 + (lane >> 3);
        const int cg = (lane & 7) ^ (lane >> 3);
        aoff[i] = (size_t)(m0 + row) * Kd + cg * 8;
        boff[i] = (size_t)(n0 + row) * Kd + cg * 8;
    }

    ffrag4 acc[4][4];
#pragma unroll
    for (int mi = 0; mi < 4; ++mi)
#pragma unroll
        for (int ni = 0; ni < 4; ++ni) acc[mi][ni] = (ffrag4){0.f, 0.f, 0.f, 0.f};

    for (int k0 = 0; k0 < Kd; k0 += 64) {
#pragma unroll
        for (int i = 0; i < 4; ++i) {
            gload_lds16(A + aoff[i] + k0, &As[(i * 4 + w) * 512]);
            gload_lds16(BT + boff[i] + k0, &Bs[(i * 4 + w) * 512]);
        }
        __syncthreads();

#pragma unroll
        for (int kk = 0; kk < 2; ++kk) {
            sfrag8 af[4], bfv[4];
#pragma unroll
            for (int mi = 0; mi < 4; ++mi) {
                const int row = wm * 64 + mi * 16 + ln;
                const int pc = ((kk * 4) | quad) ^ (ln & 7);
                af[mi] = *(const sfrag8*)&As[row * 64 + pc * 8];
            }
#pragma unroll
            for (int ni = 0; ni < 4; ++ni) {
                const int row = wn * 64 + ni * 16 + ln;
                const int pc = ((kk * 4) | quad) ^ (ln & 7);
                bfv[ni] = *(const sfrag8*)&Bs[row * 64 + pc * 8];
            }
#pragma unroll
            for (int mi = 0; mi < 4; ++mi)
#pragma unroll
                for (int ni = 0; ni < 4; ++ni)
                    acc[mi][ni] = __builtin_amdgcn_mfma_f32_16x16x32_bf16(
                        af[mi], bfv[ni], acc[mi][ni], 0, 0, 0);
        }
        __syncthreads();
    }

    if constexpr (CMODE == 4) {
        u16* base = (u16*)Cp;   // workspace base
        if (n0 < 5120) {
            // ---- rope path (Q or K head). Stage acc tile as bf16. ----
#pragma unroll
            for (int mi = 0; mi < 4; ++mi)
#pragma unroll
                for (int ni = 0; ni < 4; ++ni) {
                    const int colL = wn * 64 + ni * 16 + ln;
#pragma unroll
                    for (int i = 0; i < 4; ++i) {
                        const int rowL = wm * 64 + mi * 16 + quad * 4 + i;
                        SmemAll[rowL * 128 + colL] = f2bf(acc[mi][ni][i]);
                    }
                }
            __syncthreads();
            float invf[4];
#pragma unroll
            for (int ni = 0; ni < 4; ++ni)
                invf[ni] = EXP2F((float)(ni * 16 + ln) * NEG_L2_THETA_64);
#pragma unroll
            for (int mi = 0; mi < 4; ++mi)
#pragma unroll
                for (int ni = 0; ni < 4; ++ni) {
                    const int colL = wn * 64 + ni * 16 + ln;
                    const int fi = colL & 63;
                    const int gcol = n0 + colL;
#pragma unroll
                    for (int i = 0; i < 4; ++i) {
                        const int rowL = wm * 64 + mi * 16 + quad * 4 + i;
                        const int grow = m0 + rowL;
                        const float x1 = bf2f(SmemAll[rowL * 128 + fi]);
                        const float x2 = bf2f(SmemAll[rowL * 128 + fi + 64]);
                        const float ang = (float)grow * invf[ni];
                        const float cw = cosf(ang);
                        const float sw = sinf(ang);
                        const float o = (wn == 0) ? (x1 * cw - x2 * sw)
                                                  : (x2 * cw + x1 * sw);
                        const u16 v = f2bf(o);
                        if (gcol < 4096) {          // qsl at ws+8MiB
                            base[4194304u + (size_t)grow * 4096 + gcol] = v;
                        } else {                    // kbuf at ws+0
                            base[(size_t)grow * 1024 + (gcol - 4096)] = v;
                        }
                    }
                }
        } else {
            // ---- V region: direct transposed store, no rope ----
#pragma unroll
            for (int mi = 0; mi < 4; ++mi)
#pragma unroll
                for (int ni = 0; ni < 4; ++ni) {
                    const int gcol = n0 + wn * 64 + ni * 16 + ln;
#pragma unroll
                    for (int i = 0; i < 4; ++i) {
                        const int grow = m0 + wm * 64 + mi * 16 + quad * 4 + i;
                        base[2097152u + (size_t)(gcol - 5120) * T_SEQ + grow] =
                            f2bf(acc[mi][ni][i]);
                    }
                }
        }
        return;
    }

#pragma unroll
    for (int mi = 0; mi < 4; ++mi) {
#pragma unroll
        for (int ni = 0; ni < 4; ++ni) {
            const int gcol = n0 + wn * 64 + ni * 16 + ln;
#pragma unroll
            for (int i = 0; i < 4; ++i) {
                const int grow = m0 + wm * 64 + mi * 16 + quad * 4 + i;
                if constexpr (CMODE == 1) {
                    ((float*)Cp)[(size_t)grow * ldc + gcol] = acc[mi][ni][i];
                } else {
                    ((u16*)Cp)[(size_t)grow * ldc + gcol] = f2bf(acc[mi][ni][i]);
                }
            }
        }
    }
}

// ---------------------------------------------------------------------------
// OLD GEMM (fallback path only).
// ---------------------------------------------------------------------------
template <int AMODE, int CMODE>
__global__ __launch_bounds__(256) void gemm_any(
    const void* __restrict__ Ap, const float* __restrict__ B, void* __restrict__ Cp,
    int M, int Nb, int Kd, int ldc)
{
    __shared__ __align__(16) u16 As[64 * 64];
    __shared__ __align__(16) u16 Bs[64 * 72];

    const int tid = threadIdx.x;
    const int n0 = blockIdx.x * 64, m0 = blockIdx.y * 64;

    const int lr = tid >> 3;
    const int cc8 = tid & 7;
    const int sw = ((cc8 ^ (lr & 7)) * 8);
    const int dstA0 = lr * 64 + sw;
    const int dstA1 = (lr + 32) * 64 + sw;
    const size_t arow0 = (size_t)(m0 + lr) * Kd;
    const size_t arow1 = (size_t)(m0 + lr + 32) * Kd;

    const int kr = tid >> 2;
    const int ncb = (tid & 3) * 16;

    const int lane = tid & 63;
    const int w = tid >> 6;
    const int col16 = lane & 15;
    const int quad = lane >> 4;
    const int swl = lane & 7;
    const int mrow = w * 16 + col16;

    ffrag4 acc[4];
#pragma unroll
    for (int j = 0; j < 4; ++j) acc[j] = (ffrag4){0.f, 0.f, 0.f, 0.f};

    for (int k0 = 0; k0 < Kd; k0 += 64) {
        if constexpr (AMODE == 1) {
            const u16* Af = (const u16*)Ap;
            uint4 va0 = *(const uint4*)(Af + arow0 + k0 + cc8 * 8);
            uint4 va1 = *(const uint4*)(Af + arow1 + k0 + cc8 * 8);
            *(uint4*)&As[dstA0] = va0;
            *(uint4*)&As[dstA1] = va1;
        } else {
            const float* Af = (const float*)Ap;
            float4 a00 = *(const float4*)(Af + arow0 + k0 + cc8 * 8);
            float4 a01 = *(const float4*)(Af + arow0 + k0 + cc8 * 8 + 4);
            float4 a10 = *(const float4*)(Af + arow1 + k0 + cc8 * 8);
            float4 a11 = *(const float4*)(Af + arow1 + k0 + cc8 * 8 + 4);
            *(uint4*)&As[dstA0] = pack8(a00, a01);
            *(uint4*)&As[dstA1] = pack8(a10, a11);
        }
        {
            const float* bp = B + (size_t)(k0 + kr) * Nb + n0 + ncb;
            float4 b0 = *(const float4*)(bp);
            float4 b1 = *(const float4*)(bp + 4);
            float4 b2 = *(const float4*)(bp + 8);
            float4 b3 = *(const float4*)(bp + 12);
            u16 tmp[16];
            tmp[0] = f2bf(b0.x); tmp[1] = f2bf(b0.y); tmp[2] = f2bf(b0.z); tmp[3] = f2bf(b0.w);
            tmp[4] = f2bf(b1.x); tmp[5] = f2bf(b1.y); tmp[6] = f2bf(b1.z); tmp[7] = f2bf(b1.w);
            tmp[8] = f2bf(b2.x); tmp[9] = f2bf(b2.y); tmp[10] = f2bf(b2.z); tmp[11] = f2bf(b2.w);
            tmp[12] = f2bf(b3.x); tmp[13] = f2bf(b3.y); tmp[14] = f2bf(b3.z); tmp[15] = f2bf(b3.w);
#pragma unroll
            for (int e = 0; e < 16; ++e)
                Bs[(ncb + e) * 72 + kr] = tmp[e];
        }
        __syncthreads();
#pragma unroll
        for (int c = 0; c < 2; ++c) {
            const int cc = c * 4 + quad;
            const int koffA = (cc ^ swl) * 8;
            sfrag8 af = *(const sfrag8*)&As[mrow * 64 + koffA];
#pragma unroll
            for (int j = 0; j < 4; ++j) {
                sfrag8 bfv = *(const sfrag8*)&Bs[(j * 16 + col16) * 72 + cc * 8];
                acc[j] = __builtin_amdgcn_mfma_f32_16x16x32_bf16(af, bfv, acc[j], 0, 0, 0);
            }
        }
        __syncthreads();
    }

#pragma unroll
    for (int j = 0; j < 4; ++j) {
        const int gcol = n0 + j * 16 + col16;
#pragma unroll
        for (int i = 0; i < 4; ++i) {
            const int grow = m0 + w * 16 + quad * 4 + i;
            if constexpr (CMODE == 1) {
                ((float*)Cp)[(size_t)grow * ldc + gcol] = acc[j][i];
            } else if constexpr (CMODE == 2) {
                ((u16*)Cp)[(size_t)gcol * ldc + grow] = f2bf(acc[j][i]);
            } else {
                ((u16*)Cp)[(size_t)grow * ldc + gcol] = f2bf(acc[j][i]);
            }
        }
    }
}

// ---------------------------------------------------------------------------
// RoPE in-place (fallback path only). grid (nheads, rows).
// ---------------------------------------------------------------------------
__global__ __launch_bounds__(64) void rope_kernel(
    u16* __restrict__ buf, int nheads, int t0)
{
    const int h = blockIdx.x;
    const int t = blockIdx.y;
    u16* rowp = buf + ((size_t)t * nheads + h) * HEAD_DIM;
    const int i = threadIdx.x;  // 0..63
    const float p = (float)(t0 + t);
    const float inv = expf(-((float)i * (1.0f / 64.0f)) * 13.122363377404329f);
    const float ang = p * inv;
    const float c = cosf(ang);
    const float s = sinf(ang);
    const float x1 = bf2f(rowp[i]);
    const float x2 = bf2f(rowp[i + 64]);
    rowp[i] = f2bf(x1 * c - x2 * s);
    rowp[i + 64] = f2bf(x2 * c + x1 * s);
}

// ---------------------------------------------------------------------------
// MFMA flash attention, causal, GQA. grid (N_HEADS, Ts/64), block 256 (4
// waves). Round-6 verified softmax (defer-max THR=8, exp2, lane-local l,
// setprio, longest-first qt) + NEW double-buffered global_load_lds staging:
// Kt/Vt unpadded XOR-swizzled (chunk ^= row&7, 16B chunks; inverse swizzle on
// the GLOBAL source per rule #21 -- same proven pattern as gemm_bt, which
// measures 0 bank conflicts). One barrier per tile: barrier drains buf[cur]'s
// async loads, then next tile is issued into buf[cur^1] and flies under this
// tile's compute. No staging registers (round-3's spill is impossible here).
// ---------------------------------------------------------------------------
__global__ __launch_bounds__(256) void attn_mfma(
    const u16* q, const u16* __restrict__ k,
    const u16* __restrict__ vt, u16* ctx, int t0)
{
    __shared__ __align__(16) u16 Ktb[2][64 * 128];   // [buf][key][d] swizzled
    __shared__ __align__(16) u16 Vtb[2][128 * 64];   // [buf][d][key] swizzled
    __shared__ __align__(16) u16 Ps[4][16 * 72];     // per-wave [q][key], pad 8

    const int head = blockIdx.x;
    const int qt = gridDim.y - 1 - blockIdx.y;      // longest-first dispatch
    const int kvh = head >> 2;
    const int tid = threadIdx.x;
    const int lane = tid & 63;
    const int w = tid >> 6;          // wave id
    const int ln = lane & 15;
    const int quad = lane >> 4;

    // Q fragments: A[m=ln][k=kk*32+quad*8+j]  (Q already roped)
    const int qrow_loc = qt * 64 + w * 16 + ln;
    sfrag8 qf[4];
    {
        const u16* qg = q + ((size_t)qrow_loc * N_HEADS + head) * HEAD_DIM;
#pragma unroll
        for (int kk = 0; kk < 4; ++kk)
            qf[kk] = *(const sfrag8*)(qg + kk * 32 + quad * 8);
    }

    // async staging: per wave-issue seg (0..15), K covers 4 rows x 256B,
    // V covers 8 rows x 128B. Global chunk pre-swizzled: cg = cl ^ (row&7).
    const int krow_l = lane >> 4;    // 0..3  (row within K segment)
    const int kcl    = lane & 15;    // 16B chunk within 256B row
    const int vrow_l = lane >> 3;    // 0..7  (row within V segment)
    const int vcl    = lane & 7;     // 16B chunk within 128B row

    auto stage = [&](int kv0s, int buf) {
#pragma unroll
        for (int i = 0; i < 4; ++i) {
            const int seg = i * 4 + w;
            const int krow = seg * 4 + krow_l;
            const int kcg = kcl ^ (krow & 7);
            gload_lds16(
                k + ((size_t)(kv0s + krow) * K_HEADS + kvh) * HEAD_DIM + kcg * 8,
                &Ktb[buf][seg * 512]);
            const int vrow = seg * 8 + vrow_l;
            const int vcg = vcl ^ (vrow & 7);
            gload_lds16(
                vt + ((size_t)(kvh * 128 + vrow)) * T_SEQ + kv0s + vcg * 8,
                &Vtb[buf][seg * 512]);
        }
    };

    ffrag4 acc_o[8];
#pragma unroll
    for (int dt = 0; dt < 8; ++dt) acc_o[dt] = (ffrag4){0.f, 0.f, 0.f, 0.f};
    float mrow[4] = {-INFINITY, -INFINITY, -INFINITY, -INFINITY};
    float lrow_l[4] = {0.f, 0.f, 0.f, 0.f};   // lane-local partial sums

    const int Tq0 = t0 + qt * 64;           // absolute base of q tile
    const int nst = Tq0 / 64 + 1;           // KV tiles incl. diagonal
    const int qabs_base = Tq0 + w * 16 + quad * 4;  // + i = abs q row

    stage(0, 0);          // prologue: tile 0 -> buf 0
    int cur = 0;

    for (int st = 0; st < nst; ++st) {
        const int kv0 = st * 64;
        const bool diag = (st == nst - 1);

        __syncthreads();   // drains buf[cur] loads; prev compute done
        if (st + 1 < nst) stage(kv0 + 64, cur ^ 1);   // flies under compute

        const int ktc = diag ? ((w < 2) ? 2 : 4) : 4;   // key subtiles computed
        // ---- S = Q K^T ----
        ffrag4 sacc[4];
        __builtin_amdgcn_s_setprio(1);
#pragma unroll
        for (int kt = 0; kt < 4; ++kt) {
            if (kt >= ktc) break;
            sacc[kt] = (ffrag4){0.f, 0.f, 0.f, 0.f};
#pragma unroll
            for (int kk = 0; kk < 4; ++kk) {
                sfrag8 bfr = *(const sfrag8*)&Ktb[cur][
                    (kt * 16 + ln) * 128 + (((kk * 4 + quad) ^ (ln & 7)) * 8)];
                sacc[kt] = __builtin_amdgcn_mfma_f32_16x16x32_bf16(qf[kk], bfr, sacc[kt], 0, 0, 0);
            }
        }
        __builtin_amdgcn_s_setprio(0);
        // ---- scale (exp2 domain) + causal mask ----
        float sv[4][4];
#pragma unroll
        for (int kt = 0; kt < 4; ++kt) {
            if (kt >= ktc) break;
            const int key_abs = kv0 + kt * 16 + ln;
#pragma unroll
            for (int i = 0; i < 4; ++i) {
                float s = sacc[kt][i] * QSCALE_LOG2E;
                if (diag && key_abs > qabs_base + i) s = -INFINITY;
                sv[kt][i] = s;
            }
        }
        // ---- defer-max (T13): only reduce/rescale when max grew > THR ----
        bool grew = false;
#pragma unroll
        for (int kt = 0; kt < 4; ++kt) {
            if (kt >= ktc) break;
#pragma unroll
            for (int i = 0; i < 4; ++i)
                grew |= (sv[kt][i] > mrow[i] + 8.0f);
        }
        if (__any(grew)) {
            float tm[4];
#pragma unroll
            for (int i = 0; i < 4; ++i) {
                float t = sv[0][i];
                for (int kt = 1; kt < ktc; ++kt) t = fmaxf(t, sv[kt][i]);
                t = fmaxf(t, __shfl_xor(t, 1));
                t = fmaxf(t, __shfl_xor(t, 2));
                t = fmaxf(t, __shfl_xor(t, 4));
                t = fmaxf(t, __shfl_xor(t, 8));
                tm[i] = t;
            }
            float alpha[4];
#pragma unroll
            for (int i = 0; i < 4; ++i) {
                const float mn = fmaxf(mrow[i], tm[i]);
                alpha[i] = EXP2F(mrow[i] - mn);
                mrow[i] = mn;
            }
            const bool noop = (alpha[0] == 1.f) && (alpha[1] == 1.f) &&
                              (alpha[2] == 1.f) && (alpha[3] == 1.f);
            if (!__all(noop)) {
#pragma unroll
                for (int i = 0; i < 4; ++i) {
                    lrow_l[i] *= alpha[i];
#pragma unroll
                    for (int dt = 0; dt < 8; ++dt) acc_o[dt][i] *= alpha[i];
                }
            }
        }
        // ---- P = exp2(S - m), write to Ps, accumulate lane-local l ----
#pragma unroll
        for (int kt = 0; kt < 4; ++kt) {
            if (kt >= ktc) break;
#pragma unroll
            for (int i = 0; i < 4; ++i) {
                const float p = EXP2F(sv[kt][i] - mrow[i]);
                lrow_l[i] += p;
                Ps[w][(quad * 4 + i) * 72 + kt * 16 + ln] = f2bf(p);
            }
        }
        // ---- O += P V ----
        const int kbm = ktc >> 1;
        __builtin_amdgcn_s_setprio(1);
#pragma unroll
        for (int kb = 0; kb < 2; ++kb) {
            if (kb >= kbm) break;
            sfrag8 afr = *(const sfrag8*)&Ps[w][ln * 72 + kb * 32 + quad * 8];
#pragma unroll
            for (int dt = 0; dt < 8; ++dt) {
                sfrag8 bfr = *(const sfrag8*)&Vtb[cur][
                    (dt * 16 + ln) * 64 + (((kb * 4 + quad) ^ (ln & 7)) * 8)];
                acc_o[dt] = __builtin_amdgcn_mfma_f32_16x16x32_bf16(afr, bfr, acc_o[dt], 0, 0, 0);
            }
        }
        __builtin_amdgcn_s_setprio(0);
        cur ^= 1;
    }

    // ---- final l reduction (once) + write ctx ----
    float invl[4];
#pragma unroll
    for (int i = 0; i < 4; ++i) {
        float t = lrow_l[i];
        t += __shfl_xor(t, 1);
        t += __shfl_xor(t, 2);
        t += __shfl_xor(t, 4);
        t += __shfl_xor(t, 8);
        invl[i] = 1.0f / t;
    }
#pragma unroll
    for (int i = 0; i < 4; ++i) {
        u16* og = ctx + ((size_t)(qt * 64 + w * 16 + quad * 4 + i) * N_HEADS + head) * HEAD_DIM;
#pragma unroll
        for (int dt = 0; dt < 8; ++dt)
            og[dt * 16 + ln] = f2bf(acc_o[dt][i] * invl[i]);
    }
}

// ---------------------------------------------------------------------------
extern "C" void kernel_launch(void* const* d_in, const int* in_sizes, int n_in,
                              void* d_out, int out_size, void* d_ws, size_t ws_size,
                              hipStream_t stream) {
    (void)in_sizes; (void)n_in; (void)out_size;
    const float* x  = (const float*)d_in[0];
    const float* Wq = (const float*)d_in[2];
    const float* Wk = (const float*)d_in[3];
    const float* Wv = (const float*)d_in[4];
    const float* Wo = (const float*)d_in[5];
    float* out = (float*)d_out;
    char* ws = (char*)d_ws;
    const size_t MiB = 1024 * 1024;

    if (ws_size >= 88 * MiB) {
        // Layout: kbuf 0..4 | vtbuf 4..8 | qsl 8..24 | xb 24..40 |
        //         WqkvT 40..88 (6144 x 4096 bf16; reused for WoT)   [MiB]
        u16* kbuf  = (u16*)(ws);
        u16* vtbuf = (u16*)(ws + 4 * MiB);
        u16* qsl   = (u16*)(ws + 8 * MiB);
        u16* xb    = (u16*)(ws + 24 * MiB);
        u16* WqkvT = (u16*)(ws + 40 * MiB);

        convert_bf16<<<dim3(T_SEQ * D_MODEL / 8 / 256), 256, 0, stream>>>(
            x, xb, T_SEQ * D_MODEL / 8);
        // weights -> B^T bf16: rows 0..4095 Wq^T, 4096..5119 Wk^T, 5120..6143 Wv^T
        transpose_f32_bf16<<<dim3(64, 64), 256, 0, stream>>>(
            Wq, WqkvT, D_MODEL, N_HEADS * HEAD_DIM);
        transpose_f32_bf16<<<dim3(16, 64), 256, 0, stream>>>(
            Wk, WqkvT + (size_t)4096 * 4096, D_MODEL, K_HEADS * HEAD_DIM);
        transpose_f32_bf16<<<dim3(16, 64), 256, 0, stream>>>(
            Wv, WqkvT + (size_t)5120 * 4096, D_MODEL, K_HEADS * HEAD_DIM);

        // fused Q+K+V projection + RoPE: one GEMM, routed epilogue (CMODE 4)
        gemm_bt<4><<<dim3(48, 16), 256, 0, stream>>>(
            xb, WqkvT, ws, T_SEQ, 6144, D_MODEL, 0);

        // attention (ctx in-place in qsl)
        attn_mfma<<<dim3(N_HEADS, T_SEQ / 64), 256, 0, stream>>>(
            qsl, kbuf, vtbuf, qsl, 0);

        // output projection (WqkvT region reused for Wo^T; in-order stream)
        transpose_f32_bf16<<<dim3(64, 64), 256, 0, stream>>>(
            Wo, WqkvT, N_HEADS * HEAD_DIM, D_MODEL);
        gemm_bt<1><<<dim3(32, 16), 256, 0, stream>>>(
            qsl, WqkvT, out, T_SEQ, D_MODEL, N_HEADS * HEAD_DIM, D_MODEL);
        return;
    }

    // ------------------- fallback: previous verified path -------------------
    u16* kbuf  = (u16*)(ws);                 // [t][kvh][d]   4,194,304 B
    u16* vtbuf = (u16*)(ws + 4194304);       // [kvh*128+d][t] 4,194,304 B
    u16* qsl   = (u16*)(ws + 8388608);       // [t][h][d] slice

    int S = 8;
    if (ws_size >= (size_t)8388608 + 16777216)      S = 1;
    else if (ws_size >= (size_t)8388608 + 8388608)  S = 2;
    else if (ws_size >= (size_t)8388608 + 4194304)  S = 4;
    const int Ts = T_SEQ / S;

    gemm_any<0, 0><<<dim3(16, T_SEQ / 64), 256, 0, stream>>>(
        x, Wk, kbuf, T_SEQ, K_HEADS * HEAD_DIM, D_MODEL, K_HEADS * HEAD_DIM);
    gemm_any<0, 2><<<dim3(16, T_SEQ / 64), 256, 0, stream>>>(
        x, Wv, vtbuf, T_SEQ, K_HEADS * HEAD_DIM, D_MODEL, T_SEQ);
    rope_kernel<<<dim3(K_HEADS, T_SEQ), 64, 0, stream>>>(kbuf, K_HEADS, 0);

    for (int s = 0; s < S; ++s) {
        const int t0 = s * Ts;
        gemm_any<0, 0><<<dim3(64, Ts / 64), 256, 0, stream>>>(
            x + (size_t)t0 * D_MODEL, Wq, qsl, Ts, D_MODEL, D_MODEL, D_MODEL);
        rope_kernel<<<dim3(N_HEADS, Ts), 64, 0, stream>>>(qsl, N_HEADS, t0);
        attn_mfma<<<dim3(N_HEADS, Ts / 64), 256, 0, stream>>>(
            qsl, kbuf, vtbuf, qsl, t0);
        gemm_any<1, 1><<<dim3(64, Ts / 64), 256, 0, stream>>>(
            qsl, Wo, out + (size_t)t0 * D_MODEL, Ts, D_MODEL, N_HEADS * HEAD_DIM, D_MODEL);
    }
}